// Round 3
// baseline (406.963 us; speedup 1.0000x reference)
//
#include <hip/hip_runtime.h>
#include <math.h>

typedef __bf16 bf16;
typedef __bf16 bf16x4 __attribute__((ext_vector_type(4)));
typedef __bf16 bf16x8 __attribute__((ext_vector_type(8)));
typedef float  f32x4  __attribute__((ext_vector_type(4)));

__device__ __forceinline__ f32x4 mfma16x16x32(bf16x8 a, bf16x8 b, f32x4 c) {
  return __builtin_amdgcn_mfma_f32_16x16x32_bf16(a, b, c, 0, 0, 0);
}

// async 16B global -> LDS (lane data lands at ldsbase + lane*16)
__device__ __forceinline__ void async16(const bf16* gp, bf16* lp) {
  __builtin_amdgcn_global_load_lds(
      (const __attribute__((address_space(1))) void*)gp,
      (__attribute__((address_space(3))) void*)lp, 16, 0, 0);
}

// ---------------- fp32 -> bf16 convert ----------------
__global__ void __launch_bounds__(256) convert_bf16_kernel(const float* __restrict__ in,
                                                           bf16* __restrict__ out, int n4) {
  int i = blockIdx.x * 256 + threadIdx.x;
  if (i < n4) {
    float4 f = ((const float4*)in)[i];
    bf16x4 b = {(bf16)f.x, (bf16)f.y, (bf16)f.z, (bf16)f.w};
    ((bf16x4*)out)[i] = b;
  }
}

// convert + zero-fill pad region [n4, n4tot) — keeps MFMA inputs NaN-free
__global__ void __launch_bounds__(256) convert_pad_kernel(const float* __restrict__ in,
                                                          bf16* __restrict__ out,
                                                          int n4, int n4tot) {
  int i = blockIdx.x * 256 + threadIdx.x;
  if (i >= n4tot) return;
  bf16x4 b = {(bf16)0.f, (bf16)0.f, (bf16)0.f, (bf16)0.f};
  if (i < n4) {
    float4 f = ((const float4*)in)[i];
    b = (bf16x4){(bf16)f.x, (bf16)f.y, (bf16)f.z, (bf16)f.w};
  }
  ((bf16x4*)out)[i] = b;
}

// w3 [67735][16] fp32 -> W3b [67840][32] bf16, k 16..31 zeroed, pad rows zeroed
__global__ void __launch_bounds__(256) convert_w3_kernel(const float* __restrict__ w3,
                                                         bf16* __restrict__ W3b,
                                                         int n4, int n4tot) {
  int i = blockIdx.x * 256 + threadIdx.x;
  if (i >= n4tot) return;
  int row = i >> 2, kq = i & 3;
  bf16x4 z = {(bf16)0.f, (bf16)0.f, (bf16)0.f, (bf16)0.f};
  bf16x4 b = z;
  if (i < n4) {
    float4 f = *(const float4*)&w3[(size_t)i * 4];
    b = (bf16x4){(bf16)f.x, (bf16)f.y, (bf16)f.z, (bf16)f.w};
  }
  *(bf16x4*)&W3b[(size_t)row * 32 + kq * 4] = b;
  *(bf16x4*)&W3b[(size_t)row * 32 + 16 + kq * 4] = z;
}

// P [1024][dX] fp32 -> Pt [*][1024] bf16 (transpose+convert, zero-pad cols>=dX)
__global__ void __launch_bounds__(256) transpose_convert_kernel(const float* __restrict__ P,
                                                                bf16* __restrict__ Pt, int dX) {
  __shared__ float t[32][33];
  int tx = threadIdx.x & 31, ty = threadIdx.x >> 5;
  int k0 = blockIdx.x * 32, c0 = blockIdx.y * 32;
#pragma unroll
  for (int s = 0; s < 4; ++s) {
    int k = k0 + ty + s * 8, col = c0 + tx;
    t[ty + s * 8][tx] = (col < dX) ? P[(size_t)k * dX + col] : 0.f;
  }
  __syncthreads();
#pragma unroll
  for (int s = 0; s < 4; ++s) {
    int colo = c0 + ty + s * 8;
    Pt[(size_t)colo * 1024 + k0 + tx] = (bf16)t[tx][ty + s * 8];
  }
}

// ---------------- row compaction by target cluster ----------------
__global__ void __launch_bounds__(1024) compact_kernel(const int* __restrict__ target,
                                                       int* __restrict__ rowmap,
                                                       int* __restrict__ slotmap,
                                                       int* __restrict__ counts) {
  __shared__ int cnt[3];
  int tid = threadIdx.x;
  if (tid < 3) cnt[tid] = 0;
  for (int i = tid; i < 3 * 1152; i += 1024) rowmap[i] = 0;
  __syncthreads();
  int t = target[tid];
  int c = (t >= 200000) ? 2 : (t >= 40000) ? 1 : (t >= 20000) ? 0 : -1;
  int slot = -1;
  if (c >= 0) {
    slot = atomicAdd(&cnt[c], 1);
    rowmap[c * 1152 + slot] = tid;
  }
  slotmap[tid] = slot;
  __syncthreads();
  if (tid < 3) counts[tid] = cnt[tid];
}

// ---------------- unified MFMA GEMM (128x128 tile, 2-phase dbuf pipeline) ----------------
// Projection GEMM (LSE=false), head and cluster-1 (K-loop shapes, KDIM>=256).
// T3-minimum schedule: stage tile kt+1 is ISSUED before compute on tile kt; the
// single __syncthreads per K-step drains loads whose latency was covered by the
// compute phase. Double-buffered LDS (64KB -> 2 blocks/CU).
template <int KDIM, bool LSE>
__global__ void __launch_bounds__(256) gemm_kernel(
    const bf16* __restrict__ A, int strideA,
    const int* __restrict__ rmap, const int* __restrict__ cntp,
    const bf16* __restrict__ B,
    const float* __restrict__ bias, const float* __restrict__ bias2,
    int splice, int V, float* __restrict__ part, int nchunk,
    bf16* __restrict__ Out, int strideOut, int dX) {
  constexpr int BK = 64;
  constexpr int KG = BK / 8;                    // 8 granules
  constexpr int NIT = KDIM / BK;
  __shared__ bf16 Alds[2][128 * BK];
  __shared__ bf16 Blds[2][128 * BK];
  __shared__ float wpart[2][128];

  const int tid = threadIdx.x;
  const int w = tid >> 6, lane = tid & 63;
  const int q = lane >> 4, c = lane & 15;
  const int wr = w >> 1, wc = w & 1;

  int f = blockIdx.x;
  int xr = f & 7, rb = (f >> 3) & 7, cq = f >> 6;
  int chunk = cq * 8 + xr;
  if (chunk >= nchunk) return;
  const int row0 = rb * 128, col0 = chunk * 128;
  if (cntp && row0 >= *cntp) return;

  int arow[KG / 2];
#pragma unroll
  for (int i = 0; i < KG / 2; ++i) {
    int g = i * 256 + tid;
    int r = row0 + g / KG;
    arow[i] = rmap ? rmap[r] : r;
  }

  // stage K-tile kt into LDS buffer pb (8 async16 per thread)
  auto stage = [&](int kt, int pb) {
    const int k0 = kt * BK;
#pragma unroll
    for (int i = 0; i < KG / 2; ++i) {
      int g = i * 256 + tid;
      int col = g / KG, j = g % KG;
      int kg = j ^ (col & 7);
      async16(A + (size_t)arow[i] * strideA + k0 + kg * 8,
              &Alds[pb][(size_t)(g & ~63) * 8]);
      async16(B + (size_t)(col0 + col) * KDIM + k0 + kg * 8,
              &Blds[pb][(size_t)(g & ~63) * 8]);
    }
  };

  f32x4 acc[4][4] = {};

  stage(0, 0);
  __syncthreads();  // prologue drain

  for (int kt = 0; kt < NIT; ++kt) {
    const int cb = kt & 1;
    if (kt + 1 < NIT) stage(kt + 1, cb ^ 1);  // issue-early: lands under compute
#pragma unroll
    for (int ks = 0; ks < BK / 32; ++ks) {
      bf16x8 af[4], bfr[4];
#pragma unroll
      for (int rt = 0; rt < 4; ++rt) {
        int rl = wr * 64 + rt * 16 + c;
        int kq = ks * 4 + q;
        int kg = kq ^ (rl & 7);
        af[rt] = *(const bf16x8*)&Alds[cb][((size_t)rl * KG + kg) * 8];
      }
#pragma unroll
      for (int ct = 0; ct < 4; ++ct) {
        int cl = wc * 64 + ct * 16 + c;
        int kq = ks * 4 + q;
        int kg = kq ^ (cl & 7);
        bfr[ct] = *(const bf16x8*)&Blds[cb][((size_t)cl * KG + kg) * 8];
      }
#pragma unroll
      for (int rt = 0; rt < 4; ++rt)
#pragma unroll
        for (int ct = 0; ct < 4; ++ct)
          acc[rt][ct] = mfma16x16x32(af[rt], bfr[ct], acc[rt][ct]);
    }
    // one barrier per K-step: fences buf reuse + drains the prefetch (latency
    // already covered by the MFMA/ds_read phase above)
    __syncthreads();
  }

  if (!LSE) {
#pragma unroll
    for (int rt = 0; rt < 4; ++rt)
#pragma unroll
      for (int ct = 0; ct < 4; ++ct)
#pragma unroll
        for (int r = 0; r < 4; ++r) {
          int col = col0 + wc * 64 + ct * 16 + c;
          if (col < dX) {
            int row = row0 + wr * 64 + rt * 16 + q * 4 + r;
            Out[(size_t)row * strideOut + col] = (bf16)acc[rt][ct][r];
          }
        }
    return;
  }

  // ---- LSE epilogue, M=0 (logit spread << 87: exp cannot overflow) ----
  float bv[4];
#pragma unroll
  for (int ct = 0; ct < 4; ++ct) {
    int colg = col0 + wc * 64 + ct * 16 + c;
    bv[ct] = (colg < V) ? ((colg < splice) ? bias[colg] : bias2[colg - splice]) : -INFINITY;
  }
#pragma unroll
  for (int rt = 0; rt < 4; ++rt) {
#pragma unroll
    for (int r = 0; r < 4; ++r) {
      float s = 0.f;
#pragma unroll
      for (int ct = 0; ct < 4; ++ct) s += __expf(acc[rt][ct][r] + bv[ct]);
#pragma unroll
      for (int off = 1; off <= 8; off <<= 1) s += __shfl_xor(s, off);
      if (c == 0) wpart[wc][wr * 64 + rt * 16 + q * 4 + r] = s;
    }
  }
  __syncthreads();
  if (tid < 128)
    part[(size_t)chunk * 1024 + row0 + tid] = __logf(wpart[0][tid] + wpart[1][tid]);
}

// ---------------- wide tail GEMM+LSE: K fully resident, G chunks/block ----------------
// cluster 2: K=64, cluster 3: K=32. A-tile staged ONCE, A-fragments hoisted to
// registers. B 3-buffered with DEPTH-2 prefetch and counted vmcnt (never 0 in
// the loop). Bias pre-staged to LDS; running exp-sums in registers across all
// G chunks; one shuffle-reduce + one partial write per block.
template <int KDIM, int G>
__global__ void __launch_bounds__(256) gemm_lse_wide_kernel(
    const bf16* __restrict__ A, int strideA,
    const int* __restrict__ rmap, const int* __restrict__ cntp,
    const bf16* __restrict__ B, const float* __restrict__ bias,
    int V, float* __restrict__ part, int nchunk) {
  constexpr int BK = KDIM;          // 32 or 64
  constexpr int KG = BK / 8;        // granules per row
  constexpr int NL = KG / 2;        // async16 issued per thread per B-chunk
  __shared__ bf16 Alds[128 * BK];
  __shared__ bf16 Blds[3][128 * BK];
  __shared__ float biasl[G * 128];
  __shared__ float spart[2][128];

  const int tid = threadIdx.x;
  const int w = tid >> 6, lane = tid & 63;
  const int q = lane >> 4, c = lane & 15;
  const int wr = w >> 1, wc = w & 1;

  const int row0 = blockIdx.y * 128;
  if (row0 >= *cntp) return;
  const int chunk0 = blockIdx.x * G;
  const int nc = (nchunk - chunk0 < G) ? (nchunk - chunk0) : G;

  // ---- prologue: bias slab -> LDS, A once, B chunks 0 and 1 ----
  for (int i = tid; i < G * 128; i += 256) {
    int colg = chunk0 * 128 + i;
    biasl[i] = (colg < V) ? bias[colg] : -INFINITY;
  }
#pragma unroll
  for (int i = 0; i < NL; ++i) {
    int g = i * 256 + tid;
    int row = g / KG, j = g % KG;
    int kg = (KG == 8) ? (j ^ (row & 7)) : (j ^ ((row >> 1) & 3));
    int ar = rmap[row0 + row];
    async16(A + (size_t)ar * strideA + kg * 8, &Alds[(size_t)(g & ~63) * 8]);
  }
#pragma unroll
  for (int b = 0; b < 2; ++b) {
    int ck = (b < nc) ? b : nc - 1;
#pragma unroll
    for (int i = 0; i < NL; ++i) {
      int g = i * 256 + tid;
      int col = g / KG, j = g % KG;
      int kg = (KG == 8) ? (j ^ (col & 7)) : (j ^ ((col >> 1) & 3));
      async16(B + (size_t)((chunk0 + ck) * 128 + col) * KDIM + kg * 8,
              &Blds[b][(size_t)(g & ~63) * 8]);
    }
  }
  __syncthreads();  // one-time full drain

  // A fragments live in registers for the whole block
  bf16x8 af[BK / 32][4];
#pragma unroll
  for (int ks = 0; ks < BK / 32; ++ks)
#pragma unroll
    for (int rt = 0; rt < 4; ++rt) {
      int rl = wr * 64 + rt * 16 + c;
      int kq = ks * 4 + q;
      int kg = (KG == 8) ? (kq ^ (rl & 7)) : (kq ^ ((rl >> 1) & 3));
      af[ks][rt] = *(const bf16x8*)&Alds[((size_t)rl * KG + kg) * 8];
    }

  float sums[4][4] = {};  // [rt][r] running exp-sums across chunks
  int ib = 0;             // buffer holding chunk ci

  for (int ci = 0; ci < nc; ++ci) {
    // depth-2 prefetch: chunk ci+2 (clamped so NL stays constant) into (ib+2)%3
    {
      int pre = (ci + 2 < nc) ? ci + 2 : nc - 1;
      bf16* bw = Blds[(ib == 0) ? 2 : ib - 1];
#pragma unroll
      for (int i = 0; i < NL; ++i) {
        int g = i * 256 + tid;
        int col = g / KG, j = g % KG;
        int kg = (KG == 8) ? (j ^ (col & 7)) : (j ^ ((col >> 1) & 3));
        async16(B + (size_t)((chunk0 + pre) * 128 + col) * KDIM + kg * 8,
                &bw[(size_t)(g & ~63) * 8]);
      }
    }

    const bf16* Bl = Blds[ib];
    f32x4 acc[4][4] = {};
#pragma unroll
    for (int ks = 0; ks < BK / 32; ++ks) {
      bf16x8 bfr[4];
#pragma unroll
      for (int ct = 0; ct < 4; ++ct) {
        int cl = wc * 64 + ct * 16 + c;
        int kq = ks * 4 + q;
        int kg = (KG == 8) ? (kq ^ (cl & 7)) : (kq ^ ((cl >> 1) & 3));
        bfr[ct] = *(const bf16x8*)&Bl[((size_t)cl * KG + kg) * 8];
      }
#pragma unroll
      for (int rt = 0; rt < 4; ++rt)
#pragma unroll
        for (int ct = 0; ct < 4; ++ct)
          acc[rt][ct] = mfma16x16x32(af[ks][rt], bfr[ct], acc[rt][ct]);
    }

    // running exp-sum epilogue (bias from LDS: no vmem in loop)
    float bv[4];
#pragma unroll
    for (int ct = 0; ct < 4; ++ct) bv[ct] = biasl[ci * 128 + wc * 64 + ct * 16 + c];
#pragma unroll
    for (int rt = 0; rt < 4; ++rt)
#pragma unroll
      for (int r = 0; r < 4; ++r) {
#pragma unroll
        for (int ct = 0; ct < 4; ++ct)
          sums[rt][r] += __expf(acc[rt][ct][r] + bv[ct]);
      }

    // counted wait: the just-issued batch (NL) stays in flight; the batch for
    // chunk ci+1 (issued last iteration) is guaranteed landed.
    if constexpr (NL == 4) asm volatile("s_waitcnt vmcnt(4)" ::: "memory");
    else                   asm volatile("s_waitcnt vmcnt(2)" ::: "memory");
    __builtin_amdgcn_sched_barrier(0);
    __builtin_amdgcn_s_barrier();
    ib = (ib == 2) ? 0 : ib + 1;
  }

  // ---- once per block: reduce over the 16 c-lanes, combine wc halves, write ----
#pragma unroll
  for (int rt = 0; rt < 4; ++rt)
#pragma unroll
    for (int r = 0; r < 4; ++r) {
      float s = sums[rt][r];
#pragma unroll
      for (int off = 1; off <= 8; off <<= 1) s += __shfl_xor(s, off);
      if (c == 0) spart[wc][wr * 64 + rt * 16 + q * 4 + r] = s;
    }
  __syncthreads();  // full drain: also retires the clamped tail prefetches
  if (tid < 128)
    part[(size_t)blockIdx.x * 1024 + row0 + tid] = __logf(spart[0][tid] + spart[1][tid]);
}

// ---------------- final combine ----------------
__device__ __forceinline__ float wave_sum64(float v) {
#pragma unroll
  for (int off = 1; off < 64; off <<= 1) v += __shfl_xor(v, off);
  return v;
}
// chunk-major partials p[i*1024 + idx] hold log(sum exp) per chunk-group; values
// are small, so a single direct exp-sum pass is exact and safe.
__device__ float lse_cm(const float* __restrict__ p, int n, int idx) {
  int lane = threadIdx.x & 63;
  float s = 0.f;
  for (int i = lane; i < n; i += 64) s += __expf(p[(size_t)i * 1024 + idx]);
  s = wave_sum64(s);
  return __logf(s);
}
__device__ float dot_bw(const bf16* __restrict__ h, const float* __restrict__ wv, int K) {
  int lane = threadIdx.x & 63;
  float s = 0.f;
  for (int i = lane; i < K; i += 64) s += (float)h[i] * wv[i];
  return wave_sum64(s);
}

__global__ void __launch_bounds__(256) final_kernel(
    const int* __restrict__ target, const int* __restrict__ slotmap,
    const float* __restrict__ pH, const float* __restrict__ p1,
    const float* __restrict__ p2, const float* __restrict__ p3,
    const bf16* __restrict__ Hcat,
    const float* __restrict__ head_w, const float* __restrict__ head_b,
    const float* __restrict__ cluster_w, const float* __restrict__ cluster_b,
    const float* __restrict__ w1, const float* __restrict__ b1,
    const float* __restrict__ w2, const float* __restrict__ b2,
    const float* __restrict__ w3, const float* __restrict__ b3,
    float* __restrict__ out) {
  int wv = threadIdx.x >> 6, lane = threadIdx.x & 63;
  int row = blockIdx.x * 4 + wv;
  int t = target[row];
  const bf16* h0 = Hcat + (size_t)row * 1408;

  float lseH = lse_cm(pH, 157, row);
  float lp;
  if (t < 20000) {
    float sel = dot_bw(h0, head_w + (size_t)t * 1024, 1024) + head_b[t];
    lp = sel - lseH;
  } else {
    int i, L, KW, nch, hoff;
    const float* pp; const float* W; const float* Bb;
    if (t < 40000)        { i = 1; L = 20000;  KW = 256; nch = 157; hoff = 1024; pp = p1; W = w1; Bb = b1; }
    else if (t < 200000)  { i = 2; L = 40000;  KW = 64;  nch = 157; hoff = 1280; pp = p2; W = w2; Bb = b2; }
    else                  { i = 3; L = 200000; KW = 16;  nch = 67;  hoff = 1344; pp = p3; W = w3; Bb = b3; }
    int slot = slotmap[row];
    float lseT = lse_cm(pp, nch, slot);
    int ti = t - L;
    float tsel = dot_bw(h0 + hoff, W + (size_t)ti * KW, KW) + Bb[ti];
    int j = 3 - i;  // head_lp[:, -i] == cluster row (3-i)
    float csel = dot_bw(h0, cluster_w + (size_t)j * 1024, 1024) + cluster_b[j];
    lp = (csel - lseH) + (tsel - lseT);
  }
  if (lane == 0) out[row] = -lp;
}

extern "C" void kernel_launch(void* const* d_in, const int* in_sizes, int n_in,
                              void* d_out, int out_size, void* d_ws, size_t ws_size,
                              hipStream_t stream) {
  (void)in_sizes; (void)n_in; (void)out_size; (void)ws_size;
  const float* hidden    = (const float*)d_in[0];
  const int*   target    = (const int*)d_in[1];
  const float* head_w    = (const float*)d_in[2];
  const float* head_b    = (const float*)d_in[3];
  const float* cluster_w = (const float*)d_in[4];
  const float* cluster_b = (const float*)d_in[5];
  const float* proj0     = (const float*)d_in[6];
  const float* proj1     = (const float*)d_in[7];
  const float* proj2     = (const float*)d_in[8];
  const float* proj3     = (const float*)d_in[9];
  const float* w1 = (const float*)d_in[10];
  const float* b1 = (const float*)d_in[11];
  const float* w2 = (const float*)d_in[12];
  const float* b2 = (const float*)d_in[13];
  const float* w3 = (const float*)d_in[14];
  const float* b3 = (const float*)d_in[15];
  float* out = (float*)d_out;

  char* p = (char*)d_ws;
  bf16* hid_b = (bf16*)p; p += (size_t)1024 * 1024 * 2;
  bf16* Hcat  = (bf16*)p; p += (size_t)1024 * 1408 * 2;  // h0|h1|h2|h3 stride 1408
  bf16* Pcat  = (bf16*)p; p += (size_t)1408 * 1024 * 2;  // P0t|P1t|P2t|P3t stacked
  bf16* Wh    = (bf16*)p; p += (size_t)20096 * 1024 * 2; // head_w ++ cluster_w (++ zero pad)
  bf16* W1b   = (bf16*)p; p += (size_t)20096 * 256 * 2;
  bf16* W2b   = (bf16*)p; p += (size_t)160000 * 64 * 2;
  bf16* W3b   = (bf16*)p; p += (size_t)67840 * 32 * 2;
  float* pH   = (float*)p; p += (size_t)157 * 1024 * 4;
  float* p1   = (float*)p; p += (size_t)157 * 1024 * 4;
  float* p2   = (float*)p; p += (size_t)1250 * 1024 * 4;
  float* p3   = (float*)p; p += (size_t)530 * 1024 * 4;
  int* rowmap = (int*)p;  p += 3 * 1152 * 4;
  int* slotmap= (int*)p;  p += 1024 * 4;
  int* counts = (int*)p;  p += 3 * 4;

  compact_kernel<<<1, 1024, 0, stream>>>(target, rowmap, slotmap, counts);

  // ---- weight/input conversion (pad rows zero-filled: NaN-safe MFMA inputs) ----
  convert_bf16_kernel<<<1024, 256, 0, stream>>>(hidden, hid_b, 262144);
  convert_bf16_kernel<<<20000, 256, 0, stream>>>(head_w, Wh, 5120000);
  convert_pad_kernel<<<96, 256, 0, stream>>>(cluster_w, Wh + (size_t)20000 * 1024, 768, 24576);
  convert_pad_kernel<<<5024, 256, 0, stream>>>(w1, W1b, 1280000, 1286144);
  convert_bf16_kernel<<<10000, 256, 0, stream>>>(w2, W2b, 2560000);
  convert_w3_kernel<<<1060, 256, 0, stream>>>(w3, W3b, 270940, 271360);
  transpose_convert_kernel<<<dim3(32, 32), 256, 0, stream>>>(proj0, Pcat, 1024);
  transpose_convert_kernel<<<dim3(32, 8), 256, 0, stream>>>(proj1, Pcat + (size_t)1024 * 1024, 256);
  transpose_convert_kernel<<<dim3(32, 2), 256, 0, stream>>>(proj2, Pcat + (size_t)1280 * 1024, 64);
  transpose_convert_kernel<<<dim3(32, 1), 256, 0, stream>>>(proj3, Pcat + (size_t)1344 * 1024, 16);

  // ---- all projections in one GEMM: Hcat[1024][1376] = hid_b @ Pcat^T ----
  gemm_kernel<1024, false><<<128, 256, 0, stream>>>(hid_b, 1024, nullptr, nullptr, Pcat,
                                                    nullptr, nullptr, 0, 0, nullptr, 11,
                                                    Hcat, 1408, 1376);

  // ---- head + cluster-1: 2-phase pipelined GEMM with fused chunk LSE ----
  gemm_kernel<1024, true><<<64 * 20, 256, 0, stream>>>(Hcat, 1408, nullptr, nullptr, Wh,
                                                       head_b, cluster_b, 20000, 20003,
                                                       pH, 157, nullptr, 0, 0);
  gemm_kernel<256, true><<<64 * 20, 256, 0, stream>>>(Hcat + 1024, 1408, rowmap, counts, W1b,
                                                      b1, b1, 0x40000000, 20000,
                                                      p1, 157, nullptr, 0, 0);

  // ---- cluster 2/3: K-resident wide kernel, depth-2 counted-vmcnt pipeline ----
  gemm_lse_wide_kernel<64, 8><<<dim3(157, 8), 256, 0, stream>>>(
      Hcat + 1280, 1408, rowmap + 1152, counts + 1, W2b, b2, 160000, p2, 1250);
  gemm_lse_wide_kernel<32, 8><<<dim3(67, 8), 256, 0, stream>>>(
      Hcat + 1344, 1408, rowmap + 2304, counts + 2, W3b, b3, 67735, p3, 530);

  final_kernel<<<256, 256, 0, stream>>>(target, slotmap, pH, p1, p2, p3, Hcat,
                                        head_w, head_b, cluster_w, cluster_b,
                                        w1, b1, w2, b2, w3, b3, out);
}

// Round 4
// 390.611 us; speedup vs baseline: 1.0419x; 1.0419x over previous
//
#include <hip/hip_runtime.h>
#include <math.h>

typedef __bf16 bf16;
typedef __bf16 bf16x4 __attribute__((ext_vector_type(4)));
typedef __bf16 bf16x8 __attribute__((ext_vector_type(8)));
typedef float  f32x4  __attribute__((ext_vector_type(4)));

__device__ __forceinline__ f32x4 mfma16x16x32(bf16x8 a, bf16x8 b, f32x4 c) {
  return __builtin_amdgcn_mfma_f32_16x16x32_bf16(a, b, c, 0, 0, 0);
}

// async 16B global -> LDS (lane data lands at ldsbase + lane*16)
__device__ __forceinline__ void async16(const bf16* gp, bf16* lp) {
  __builtin_amdgcn_global_load_lds(
      (const __attribute__((address_space(1))) void*)gp,
      (__attribute__((address_space(3))) void*)lp, 16, 0, 0);
}

// ---------------- fp32 -> bf16 convert ----------------
__global__ void __launch_bounds__(256) convert_bf16_kernel(const float* __restrict__ in,
                                                           bf16* __restrict__ out, int n4) {
  int i = blockIdx.x * 256 + threadIdx.x;
  if (i < n4) {
    float4 f = ((const float4*)in)[i];
    bf16x4 b = {(bf16)f.x, (bf16)f.y, (bf16)f.z, (bf16)f.w};
    ((bf16x4*)out)[i] = b;
  }
}

// convert + zero-fill pad region [n4, n4tot) — keeps MFMA inputs NaN-free
__global__ void __launch_bounds__(256) convert_pad_kernel(const float* __restrict__ in,
                                                          bf16* __restrict__ out,
                                                          int n4, int n4tot) {
  int i = blockIdx.x * 256 + threadIdx.x;
  if (i >= n4tot) return;
  bf16x4 b = {(bf16)0.f, (bf16)0.f, (bf16)0.f, (bf16)0.f};
  if (i < n4) {
    float4 f = ((const float4*)in)[i];
    b = (bf16x4){(bf16)f.x, (bf16)f.y, (bf16)f.z, (bf16)f.w};
  }
  ((bf16x4*)out)[i] = b;
}

// w3 [67735][16] fp32 -> W3b [67840][32] bf16, k 16..31 zeroed, pad rows zeroed
__global__ void __launch_bounds__(256) convert_w3_kernel(const float* __restrict__ w3,
                                                         bf16* __restrict__ W3b,
                                                         int n4, int n4tot) {
  int i = blockIdx.x * 256 + threadIdx.x;
  if (i >= n4tot) return;
  int row = i >> 2, kq = i & 3;
  bf16x4 z = {(bf16)0.f, (bf16)0.f, (bf16)0.f, (bf16)0.f};
  bf16x4 b = z;
  if (i < n4) {
    float4 f = *(const float4*)&w3[(size_t)i * 4];
    b = (bf16x4){(bf16)f.x, (bf16)f.y, (bf16)f.z, (bf16)f.w};
  }
  *(bf16x4*)&W3b[(size_t)row * 32 + kq * 4] = b;
  *(bf16x4*)&W3b[(size_t)row * 32 + 16 + kq * 4] = z;
}

// P [1024][dX] fp32 -> Pt [*][1024] bf16 (transpose+convert, zero-pad cols>=dX)
__global__ void __launch_bounds__(256) transpose_convert_kernel(const float* __restrict__ P,
                                                                bf16* __restrict__ Pt, int dX) {
  __shared__ float t[32][33];
  int tx = threadIdx.x & 31, ty = threadIdx.x >> 5;
  int k0 = blockIdx.x * 32, c0 = blockIdx.y * 32;
#pragma unroll
  for (int s = 0; s < 4; ++s) {
    int k = k0 + ty + s * 8, col = c0 + tx;
    t[ty + s * 8][tx] = (col < dX) ? P[(size_t)k * dX + col] : 0.f;
  }
  __syncthreads();
#pragma unroll
  for (int s = 0; s < 4; ++s) {
    int colo = c0 + ty + s * 8;
    Pt[(size_t)colo * 1024 + k0 + tx] = (bf16)t[tx][ty + s * 8];
  }
}

// ---------------- row compaction by target cluster ----------------
__global__ void __launch_bounds__(1024) compact_kernel(const int* __restrict__ target,
                                                       int* __restrict__ rowmap,
                                                       int* __restrict__ slotmap,
                                                       int* __restrict__ counts) {
  __shared__ int cnt[3];
  int tid = threadIdx.x;
  if (tid < 3) cnt[tid] = 0;
  for (int i = tid; i < 3 * 1152; i += 1024) rowmap[i] = 0;
  __syncthreads();
  int t = target[tid];
  int c = (t >= 200000) ? 2 : (t >= 40000) ? 1 : (t >= 20000) ? 0 : -1;
  int slot = -1;
  if (c >= 0) {
    slot = atomicAdd(&cnt[c], 1);
    rowmap[c * 1152 + slot] = tid;
  }
  slotmap[tid] = slot;
  __syncthreads();
  if (tid < 3) counts[tid] = cnt[tid];
}

// ---------------- unified MFMA GEMM (128x128 tile, BK=128, serial 2-barrier) ----------------
// Projection GEMM (LSE=false), head and cluster-1 (KDIM>=128). Occupancy is
// VGPR-capped at 2 blocks/CU (88 arch VGPR + 64 AGPR acc ~= 152 unified), so the
// 65KB single-buffered BK=128 tile is free: each staging drain amortizes over
// 64 MFMA (4x better than BK=64; halves barrier count).
template <int KDIM, bool LSE>
__global__ void __launch_bounds__(256) gemm_kernel(
    const bf16* __restrict__ A, int strideA,
    const int* __restrict__ rmap, const int* __restrict__ cntp,
    const bf16* __restrict__ B,
    const float* __restrict__ bias, const float* __restrict__ bias2,
    int splice, int V, float* __restrict__ part, int nchunk,
    bf16* __restrict__ Out, int strideOut, int dX) {
  constexpr int BK = 128;
  constexpr int KG = BK / 8;                    // 16 granules per row
  constexpr int NIT = KDIM / BK;
  __shared__ bf16 Alds[128 * BK];
  __shared__ bf16 Blds[128 * BK];
  __shared__ float wpart[2][128];

  const int tid = threadIdx.x;
  const int w = tid >> 6, lane = tid & 63;
  const int q = lane >> 4, c = lane & 15;
  const int wr = w >> 1, wc = w & 1;

  int f = blockIdx.x;
  int xr = f & 7, rb = (f >> 3) & 7, cq = f >> 6;
  int chunk = cq * 8 + xr;
  if (chunk >= nchunk) return;
  const int row0 = rb * 128, col0 = chunk * 128;
  if (cntp && row0 >= *cntp) return;

  int arow[KG / 2];  // 8 A-granules per thread
#pragma unroll
  for (int i = 0; i < KG / 2; ++i) {
    int g = i * 256 + tid;
    int r = row0 + g / KG;
    arow[i] = rmap ? rmap[r] : r;
  }

  f32x4 acc[4][4] = {};

  for (int kt = 0; kt < NIT; ++kt) {
    const int k0 = kt * BK;
#pragma unroll
    for (int i = 0; i < KG / 2; ++i) {
      int g = i * 256 + tid;
      int col = g / KG, j = g % KG;
      int kg = j ^ (col & 7);
      async16(A + (size_t)arow[i] * strideA + k0 + kg * 8,
              &Alds[(size_t)(g & ~63) * 8]);
      async16(B + (size_t)(col0 + col) * KDIM + k0 + kg * 8,
              &Blds[(size_t)(g & ~63) * 8]);
    }
    __syncthreads();  // drain: amortized over the 64 MFMA below
#pragma unroll
    for (int ks = 0; ks < BK / 32; ++ks) {
      bf16x8 af[4], bfr[4];
#pragma unroll
      for (int rt = 0; rt < 4; ++rt) {
        int rl = wr * 64 + rt * 16 + c;
        int kq = ks * 4 + q;
        int kg = kq ^ (rl & 7);
        af[rt] = *(const bf16x8*)&Alds[((size_t)rl * KG + kg) * 8];
      }
#pragma unroll
      for (int ct = 0; ct < 4; ++ct) {
        int cl = wc * 64 + ct * 16 + c;
        int kq = ks * 4 + q;
        int kg = kq ^ (cl & 7);
        bfr[ct] = *(const bf16x8*)&Blds[((size_t)cl * KG + kg) * 8];
      }
#pragma unroll
      for (int rt = 0; rt < 4; ++rt)
#pragma unroll
        for (int ct = 0; ct < 4; ++ct)
          acc[rt][ct] = mfma16x16x32(af[rt], bfr[ct], acc[rt][ct]);
    }
    __syncthreads();  // fence buffer reuse before next stage
  }

  if (!LSE) {
#pragma unroll
    for (int rt = 0; rt < 4; ++rt)
#pragma unroll
      for (int ct = 0; ct < 4; ++ct)
#pragma unroll
        for (int r = 0; r < 4; ++r) {
          int col = col0 + wc * 64 + ct * 16 + c;
          if (col < dX) {
            int row = row0 + wr * 64 + rt * 16 + q * 4 + r;
            Out[(size_t)row * strideOut + col] = (bf16)acc[rt][ct][r];
          }
        }
    return;
  }

  // ---- LSE epilogue, M=0 (logit spread << 87: exp cannot overflow) ----
  float bv[4];
#pragma unroll
  for (int ct = 0; ct < 4; ++ct) {
    int colg = col0 + wc * 64 + ct * 16 + c;
    bv[ct] = (colg < V) ? ((colg < splice) ? bias[colg] : bias2[colg - splice]) : -INFINITY;
  }
#pragma unroll
  for (int rt = 0; rt < 4; ++rt) {
#pragma unroll
    for (int r = 0; r < 4; ++r) {
      float s = 0.f;
#pragma unroll
      for (int ct = 0; ct < 4; ++ct) s += __expf(acc[rt][ct][r] + bv[ct]);
#pragma unroll
      for (int off = 1; off <= 8; off <<= 1) s += __shfl_xor(s, off);
      if (c == 0) wpart[wc][wr * 64 + rt * 16 + q * 4 + r] = s;
    }
  }
  __syncthreads();
  if (tid < 128)
    part[(size_t)chunk * 1024 + row0 + tid] = __logf(wpart[0][tid] + wpart[1][tid]);
}

// ---------------- wide tail GEMM+LSE: K fully resident, G chunks/block ----------------
// cluster 2: K=64, cluster 3: K=32. A-tile staged ONCE, A-fragments hoisted to
// registers. B 3-buffered with DEPTH-2 prefetch and counted vmcnt (never 0 in
// the loop). Bias pre-staged to LDS; running exp-sums in registers across all
// G chunks; one shuffle-reduce + one partial write per block.
template <int KDIM, int G>
__global__ void __launch_bounds__(256) gemm_lse_wide_kernel(
    const bf16* __restrict__ A, int strideA,
    const int* __restrict__ rmap, const int* __restrict__ cntp,
    const bf16* __restrict__ B, const float* __restrict__ bias,
    int V, float* __restrict__ part, int nchunk) {
  constexpr int BK = KDIM;          // 32 or 64
  constexpr int KG = BK / 8;        // granules per row
  constexpr int NL = KG / 2;        // async16 issued per thread per B-chunk
  __shared__ bf16 Alds[128 * BK];
  __shared__ bf16 Blds[3][128 * BK];
  __shared__ float biasl[G * 128];
  __shared__ float spart[2][128];

  const int tid = threadIdx.x;
  const int w = tid >> 6, lane = tid & 63;
  const int q = lane >> 4, c = lane & 15;
  const int wr = w >> 1, wc = w & 1;

  const int row0 = blockIdx.y * 128;
  if (row0 >= *cntp) return;
  const int chunk0 = blockIdx.x * G;
  const int nc = (nchunk - chunk0 < G) ? (nchunk - chunk0) : G;

  // ---- prologue: bias slab -> LDS, A once, B chunks 0 and 1 ----
  for (int i = tid; i < G * 128; i += 256) {
    int colg = chunk0 * 128 + i;
    biasl[i] = (colg < V) ? bias[colg] : -INFINITY;
  }
#pragma unroll
  for (int i = 0; i < NL; ++i) {
    int g = i * 256 + tid;
    int row = g / KG, j = g % KG;
    int kg = (KG == 8) ? (j ^ (row & 7)) : (j ^ ((row >> 1) & 3));
    int ar = rmap[row0 + row];
    async16(A + (size_t)ar * strideA + kg * 8, &Alds[(size_t)(g & ~63) * 8]);
  }
#pragma unroll
  for (int b = 0; b < 2; ++b) {
    int ck = (b < nc) ? b : nc - 1;
#pragma unroll
    for (int i = 0; i < NL; ++i) {
      int g = i * 256 + tid;
      int col = g / KG, j = g % KG;
      int kg = (KG == 8) ? (j ^ (col & 7)) : (j ^ ((col >> 1) & 3));
      async16(B + (size_t)((chunk0 + ck) * 128 + col) * KDIM + kg * 8,
              &Blds[b][(size_t)(g & ~63) * 8]);
    }
  }
  __syncthreads();  // one-time full drain

  // A fragments live in registers for the whole block
  bf16x8 af[BK / 32][4];
#pragma unroll
  for (int ks = 0; ks < BK / 32; ++ks)
#pragma unroll
    for (int rt = 0; rt < 4; ++rt) {
      int rl = wr * 64 + rt * 16 + c;
      int kq = ks * 4 + q;
      int kg = (KG == 8) ? (kq ^ (rl & 7)) : (kq ^ ((rl >> 1) & 3));
      af[ks][rt] = *(const bf16x8*)&Alds[((size_t)rl * KG + kg) * 8];
    }

  float sums[4][4] = {};  // [rt][r] running exp-sums across chunks
  int ib = 0;             // buffer holding chunk ci

  for (int ci = 0; ci < nc; ++ci) {
    // depth-2 prefetch: chunk ci+2 (clamped so NL stays constant) into (ib+2)%3
    {
      int pre = (ci + 2 < nc) ? ci + 2 : nc - 1;
      bf16* bw = Blds[(ib == 0) ? 2 : ib - 1];
#pragma unroll
      for (int i = 0; i < NL; ++i) {
        int g = i * 256 + tid;
        int col = g / KG, j = g % KG;
        int kg = (KG == 8) ? (j ^ (col & 7)) : (j ^ ((col >> 1) & 3));
        async16(B + (size_t)((chunk0 + pre) * 128 + col) * KDIM + kg * 8,
                &bw[(size_t)(g & ~63) * 8]);
      }
    }

    const bf16* Bl = Blds[ib];
    f32x4 acc[4][4] = {};
#pragma unroll
    for (int ks = 0; ks < BK / 32; ++ks) {
      bf16x8 bfr[4];
#pragma unroll
      for (int ct = 0; ct < 4; ++ct) {
        int cl = wc * 64 + ct * 16 + c;
        int kq = ks * 4 + q;
        int kg = (KG == 8) ? (kq ^ (cl & 7)) : (kq ^ ((cl >> 1) & 3));
        bfr[ct] = *(const bf16x8*)&Bl[((size_t)cl * KG + kg) * 8];
      }
#pragma unroll
      for (int rt = 0; rt < 4; ++rt)
#pragma unroll
        for (int ct = 0; ct < 4; ++ct)
          acc[rt][ct] = mfma16x16x32(af[ks][rt], bfr[ct], acc[rt][ct]);
    }

    // running exp-sum epilogue (bias from LDS: no vmem in loop)
    float bv[4];
#pragma unroll
    for (int ct = 0; ct < 4; ++ct) bv[ct] = biasl[ci * 128 + wc * 64 + ct * 16 + c];
#pragma unroll
    for (int rt = 0; rt < 4; ++rt)
#pragma unroll
      for (int r = 0; r < 4; ++r) {
#pragma unroll
        for (int ct = 0; ct < 4; ++ct)
          sums[rt][r] += __expf(acc[rt][ct][r] + bv[ct]);
      }

    // counted wait: the just-issued batch (NL) stays in flight; the batch for
    // chunk ci+1 (issued last iteration) is guaranteed landed.
    if constexpr (NL == 4) asm volatile("s_waitcnt vmcnt(4)" ::: "memory");
    else                   asm volatile("s_waitcnt vmcnt(2)" ::: "memory");
    __builtin_amdgcn_sched_barrier(0);
    __builtin_amdgcn_s_barrier();
    ib = (ib == 2) ? 0 : ib + 1;
  }

  // ---- once per block: reduce over the 16 c-lanes, combine wc halves, write ----
#pragma unroll
  for (int rt = 0; rt < 4; ++rt)
#pragma unroll
    for (int r = 0; r < 4; ++r) {
      float s = sums[rt][r];
#pragma unroll
      for (int off = 1; off <= 8; off <<= 1) s += __shfl_xor(s, off);
      if (c == 0) spart[wc][wr * 64 + rt * 16 + q * 4 + r] = s;
    }
  __syncthreads();  // full drain: also retires the clamped tail prefetches
  if (tid < 128)
    part[(size_t)blockIdx.x * 1024 + row0 + tid] = __logf(spart[0][tid] + spart[1][tid]);
}

// ---------------- final combine ----------------
__device__ __forceinline__ float wave_sum64(float v) {
#pragma unroll
  for (int off = 1; off < 64; off <<= 1) v += __shfl_xor(v, off);
  return v;
}
// chunk-major partials p[i*1024 + idx] hold log(sum exp) per chunk-group; values
// are small, so a single direct exp-sum pass is exact and safe.
__device__ float lse_cm(const float* __restrict__ p, int n, int idx) {
  int lane = threadIdx.x & 63;
  float s = 0.f;
  for (int i = lane; i < n; i += 64) s += __expf(p[(size_t)i * 1024 + idx]);
  s = wave_sum64(s);
  return __logf(s);
}
__device__ float dot_bw(const bf16* __restrict__ h, const float* __restrict__ wv, int K) {
  int lane = threadIdx.x & 63;
  float s = 0.f;
  for (int i = lane; i < K; i += 64) s += (float)h[i] * wv[i];
  return wave_sum64(s);
}

__global__ void __launch_bounds__(256) final_kernel(
    const int* __restrict__ target, const int* __restrict__ slotmap,
    const float* __restrict__ pH, const float* __restrict__ p1,
    const float* __restrict__ p2, const float* __restrict__ p3,
    const bf16* __restrict__ Hcat,
    const float* __restrict__ head_w, const float* __restrict__ head_b,
    const float* __restrict__ cluster_w, const float* __restrict__ cluster_b,
    const float* __restrict__ w1, const float* __restrict__ b1,
    const float* __restrict__ w2, const float* __restrict__ b2,
    const float* __restrict__ w3, const float* __restrict__ b3,
    float* __restrict__ out) {
  int wv = threadIdx.x >> 6, lane = threadIdx.x & 63;
  int row = blockIdx.x * 4 + wv;
  int t = target[row];
  const bf16* h0 = Hcat + (size_t)row * 1408;

  float lseH = lse_cm(pH, 157, row);
  float lp;
  if (t < 20000) {
    float sel = dot_bw(h0, head_w + (size_t)t * 1024, 1024) + head_b[t];
    lp = sel - lseH;
  } else {
    int i, L, KW, nch, hoff;
    const float* pp; const float* W; const float* Bb;
    if (t < 40000)        { i = 1; L = 20000;  KW = 256; nch = 157; hoff = 1024; pp = p1; W = w1; Bb = b1; }
    else if (t < 200000)  { i = 2; L = 40000;  KW = 64;  nch = 157; hoff = 1280; pp = p2; W = w2; Bb = b2; }
    else                  { i = 3; L = 200000; KW = 16;  nch = 67;  hoff = 1344; pp = p3; W = w3; Bb = b3; }
    int slot = slotmap[row];
    float lseT = lse_cm(pp, nch, slot);
    int ti = t - L;
    float tsel = dot_bw(h0 + hoff, W + (size_t)ti * KW, KW) + Bb[ti];
    int j = 3 - i;  // head_lp[:, -i] == cluster row (3-i)
    float csel = dot_bw(h0, cluster_w + (size_t)j * 1024, 1024) + cluster_b[j];
    lp = (csel - lseH) + (tsel - lseT);
  }
  if (lane == 0) out[row] = -lp;
}

extern "C" void kernel_launch(void* const* d_in, const int* in_sizes, int n_in,
                              void* d_out, int out_size, void* d_ws, size_t ws_size,
                              hipStream_t stream) {
  (void)in_sizes; (void)n_in; (void)out_size; (void)ws_size;
  const float* hidden    = (const float*)d_in[0];
  const int*   target    = (const int*)d_in[1];
  const float* head_w    = (const float*)d_in[2];
  const float* head_b    = (const float*)d_in[3];
  const float* cluster_w = (const float*)d_in[4];
  const float* cluster_b = (const float*)d_in[5];
  const float* proj0     = (const float*)d_in[6];
  const float* proj1     = (const float*)d_in[7];
  const float* proj2     = (const float*)d_in[8];
  const float* proj3     = (const float*)d_in[9];
  const float* w1 = (const float*)d_in[10];
  const float* b1 = (const float*)d_in[11];
  const float* w2 = (const float*)d_in[12];
  const float* b2 = (const float*)d_in[13];
  const float* w3 = (const float*)d_in[14];
  const float* b3 = (const float*)d_in[15];
  float* out = (float*)d_out;

  char* p = (char*)d_ws;
  bf16* hid_b = (bf16*)p; p += (size_t)1024 * 1024 * 2;
  bf16* Hcat  = (bf16*)p; p += (size_t)1024 * 1408 * 2;  // h0|h1|h2|h3 stride 1408
  bf16* Pcat  = (bf16*)p; p += (size_t)1408 * 1024 * 2;  // P0t|P1t|P2t|P3t stacked
  bf16* Wh    = (bf16*)p; p += (size_t)20096 * 1024 * 2; // head_w ++ cluster_w (++ zero pad)
  bf16* W1b   = (bf16*)p; p += (size_t)20096 * 256 * 2;
  bf16* W2b   = (bf16*)p; p += (size_t)160000 * 64 * 2;
  bf16* W3b   = (bf16*)p; p += (size_t)67840 * 32 * 2;
  float* pH   = (float*)p; p += (size_t)157 * 1024 * 4;
  float* p1   = (float*)p; p += (size_t)157 * 1024 * 4;
  float* p2   = (float*)p; p += (size_t)1250 * 1024 * 4;
  float* p3   = (float*)p; p += (size_t)530 * 1024 * 4;
  int* rowmap = (int*)p;  p += 3 * 1152 * 4;
  int* slotmap= (int*)p;  p += 1024 * 4;
  int* counts = (int*)p;  p += 3 * 4;

  compact_kernel<<<1, 1024, 0, stream>>>(target, rowmap, slotmap, counts);

  // ---- weight/input conversion (pad rows zero-filled: NaN-safe MFMA inputs) ----
  convert_bf16_kernel<<<1024, 256, 0, stream>>>(hidden, hid_b, 262144);
  convert_bf16_kernel<<<20000, 256, 0, stream>>>(head_w, Wh, 5120000);
  convert_pad_kernel<<<96, 256, 0, stream>>>(cluster_w, Wh + (size_t)20000 * 1024, 768, 24576);
  convert_pad_kernel<<<5024, 256, 0, stream>>>(w1, W1b, 1280000, 1286144);
  convert_bf16_kernel<<<10000, 256, 0, stream>>>(w2, W2b, 2560000);
  convert_w3_kernel<<<1060, 256, 0, stream>>>(w3, W3b, 270940, 271360);
  transpose_convert_kernel<<<dim3(32, 32), 256, 0, stream>>>(proj0, Pcat, 1024);
  transpose_convert_kernel<<<dim3(32, 8), 256, 0, stream>>>(proj1, Pcat + (size_t)1024 * 1024, 256);
  transpose_convert_kernel<<<dim3(32, 2), 256, 0, stream>>>(proj2, Pcat + (size_t)1280 * 1024, 64);
  transpose_convert_kernel<<<dim3(32, 1), 256, 0, stream>>>(proj3, Pcat + (size_t)1344 * 1024, 16);

  // ---- all projections in one GEMM: Hcat[1024][1376] = hid_b @ Pcat^T ----
  gemm_kernel<1024, false><<<128, 256, 0, stream>>>(hid_b, 1024, nullptr, nullptr, Pcat,
                                                    nullptr, nullptr, 0, 0, nullptr, 11,
                                                    Hcat, 1408, 1376);

  // ---- head + cluster-1: BK=128 GEMM with fused chunk LSE ----
  gemm_kernel<1024, true><<<64 * 20, 256, 0, stream>>>(Hcat, 1408, nullptr, nullptr, Wh,
                                                       head_b, cluster_b, 20000, 20003,
                                                       pH, 157, nullptr, 0, 0);
  gemm_kernel<256, true><<<64 * 20, 256, 0, stream>>>(Hcat + 1024, 1408, rowmap, counts, W1b,
                                                      b1, b1, 0x40000000, 20000,
                                                      p1, 157, nullptr, 0, 0);

  // ---- cluster 2/3: K-resident wide kernel, depth-2 counted-vmcnt pipeline ----
  gemm_lse_wide_kernel<64, 8><<<dim3(157, 8), 256, 0, stream>>>(
      Hcat + 1280, 1408, rowmap + 1152, counts + 1, W2b, b2, 160000, p2, 1250);
  gemm_lse_wide_kernel<32, 8><<<dim3(67, 8), 256, 0, stream>>>(
      Hcat + 1344, 1408, rowmap + 2304, counts + 2, W3b, b3, 67735, p3, 530);

  final_kernel<<<256, 256, 0, stream>>>(target, slotmap, pH, p1, p2, p3, Hcat,
                                        head_w, head_b, cluster_w, cluster_b,
                                        w1, b1, w2, b2, w3, b3, out);
}

// Round 5
// 382.768 us; speedup vs baseline: 1.0632x; 1.0205x over previous
//
#include <hip/hip_runtime.h>
#include <math.h>

typedef __bf16 bf16;
typedef __bf16 bf16x4 __attribute__((ext_vector_type(4)));
typedef __bf16 bf16x8 __attribute__((ext_vector_type(8)));
typedef float  f32x4  __attribute__((ext_vector_type(4)));

__device__ __forceinline__ f32x4 mfma16x16x32(bf16x8 a, bf16x8 b, f32x4 c) {
  return __builtin_amdgcn_mfma_f32_16x16x32_bf16(a, b, c, 0, 0, 0);
}

// async 16B global -> LDS (lane data lands at ldsbase + lane*16)
__device__ __forceinline__ void async16(const bf16* gp, bf16* lp) {
  __builtin_amdgcn_global_load_lds(
      (const __attribute__((address_space(1))) void*)gp,
      (__attribute__((address_space(3))) void*)lp, 16, 0, 0);
}

// ---------------- fused fp32 -> bf16 conversion (single launch) ----------------
// blockIdx ranges:
//   [0,1024)      hidden   -> hid_b   n4=262144
//   [1024,21024)  head_w   -> Wh      n4=5120000
//   [21024,21120) cluster_w-> Wh+20M  n4=768  tot=24576 (pad zeroed)
//   [21120,26144) w1       -> W1b     n4=1280000 tot=1286144 (pad zeroed)
//   [26144,36144) w2       -> W2b     n4=2560000
//   [36144,37204) w3       -> W3b     special [67840][32] layout, k>=16 zeroed
__global__ void __launch_bounds__(256) megaconvert_kernel(
    const float* __restrict__ hidden, const float* __restrict__ head_w,
    const float* __restrict__ cluster_w, const float* __restrict__ w1,
    const float* __restrict__ w2, const float* __restrict__ w3,
    bf16* __restrict__ hid_b, bf16* __restrict__ Wh, bf16* __restrict__ W1b,
    bf16* __restrict__ W2b, bf16* __restrict__ W3b) {
  int b = blockIdx.x;
  const float* in; bf16* out; int n4, tot; int w3mode = 0;
  if (b < 1024)       { in = hidden;    out = hid_b; n4 = 262144;  tot = 262144;  }
  else if (b < 21024) { in = head_w;    out = Wh;    n4 = 5120000; tot = 5120000; b -= 1024; }
  else if (b < 21120) { in = cluster_w; out = Wh + (size_t)20000 * 1024; n4 = 768; tot = 24576; b -= 21024; }
  else if (b < 26144) { in = w1;        out = W1b;   n4 = 1280000; tot = 1286144; b -= 21120; }
  else if (b < 36144) { in = w2;        out = W2b;   n4 = 2560000; tot = 2560000; b -= 26144; }
  else                { in = w3;        out = W3b;   n4 = 270940;  tot = 271360;  b -= 36144; w3mode = 1; }
  int i = b * 256 + threadIdx.x;
  if (i >= tot) return;
  bf16x4 z = {(bf16)0.f, (bf16)0.f, (bf16)0.f, (bf16)0.f};
  bf16x4 v = z;
  if (i < n4) {
    float4 f = ((const float4*)in)[i];
    v = (bf16x4){(bf16)f.x, (bf16)f.y, (bf16)f.z, (bf16)f.w};
  }
  if (!w3mode) {
    ((bf16x4*)out)[i] = v;
  } else {
    int row = i >> 2, kq = i & 3;
    *(bf16x4*)&out[(size_t)row * 32 + kq * 4] = v;
    *(bf16x4*)&out[(size_t)row * 32 + 16 + kq * 4] = z;
  }
}

// ---------------- all 4 projections: transpose+convert in one launch ----------------
// P [1024][dX] fp32 -> Pt [*][1024] bf16, zero-pad cols>=dX.
// blockIdx.y: [0,32) proj0 | [32,40) proj1 | [40,42) proj2 | 42 proj3
__global__ void __launch_bounds__(256) transpose_all_kernel(
    const float* __restrict__ proj0, const float* __restrict__ proj1,
    const float* __restrict__ proj2, const float* __restrict__ proj3,
    bf16* __restrict__ Pcat) {
  __shared__ float t[32][33];
  int y = blockIdx.y;
  const float* P; bf16* Pt; int dX, cy;
  if (y < 32)      { P = proj0; Pt = Pcat;                        dX = 1024; cy = y; }
  else if (y < 40) { P = proj1; Pt = Pcat + (size_t)1024 * 1024;  dX = 256;  cy = y - 32; }
  else if (y < 42) { P = proj2; Pt = Pcat + (size_t)1280 * 1024;  dX = 64;   cy = y - 40; }
  else             { P = proj3; Pt = Pcat + (size_t)1344 * 1024;  dX = 16;   cy = y - 42; }
  int tx = threadIdx.x & 31, ty = threadIdx.x >> 5;
  int k0 = blockIdx.x * 32, c0 = cy * 32;
#pragma unroll
  for (int s = 0; s < 4; ++s) {
    int k = k0 + ty + s * 8, col = c0 + tx;
    t[ty + s * 8][tx] = (col < dX) ? P[(size_t)k * dX + col] : 0.f;
  }
  __syncthreads();
#pragma unroll
  for (int s = 0; s < 4; ++s) {
    int colo = c0 + ty + s * 8;
    Pt[(size_t)colo * 1024 + k0 + tx] = (bf16)t[tx][ty + s * 8];
  }
}

// ---------------- row compaction by target cluster ----------------
__global__ void __launch_bounds__(1024) compact_kernel(const int* __restrict__ target,
                                                       int* __restrict__ rowmap,
                                                       int* __restrict__ slotmap,
                                                       int* __restrict__ counts) {
  __shared__ int cnt[3];
  int tid = threadIdx.x;
  if (tid < 3) cnt[tid] = 0;
  for (int i = tid; i < 3 * 1152; i += 1024) rowmap[i] = 0;
  __syncthreads();
  int t = target[tid];
  int c = (t >= 200000) ? 2 : (t >= 40000) ? 1 : (t >= 20000) ? 0 : -1;
  int slot = -1;
  if (c >= 0) {
    slot = atomicAdd(&cnt[c], 1);
    rowmap[c * 1152 + slot] = tid;
  }
  slotmap[tid] = slot;
  __syncthreads();
  if (tid < 3) counts[tid] = cnt[tid];
}

// ------------- unified MFMA GEMM: BK=64 dbuf, counted-vmcnt K-pipeline -------------
// stage(kt+1) is issued BEFORE computing tile kt; s_waitcnt vmcnt(8) (never 0 in
// the loop) lets the new batch stay in flight across the raw s_barrier — staging
// latency hides under the MFMA phase. Per-wave vmcnt logic: each wave's vmcnt(8)
// retires its own tile-kt loads; the barrier joins all waves. Two raw barriers
// per K-step (dbuf reuse fence), no full drain. KG=8 layout = 0 bank conflicts.
template <int KDIM, bool LSE>
__global__ void __launch_bounds__(256) gemm_kernel(
    const bf16* __restrict__ A, int strideA,
    const int* __restrict__ rmap, const int* __restrict__ cntp,
    const bf16* __restrict__ B,
    const float* __restrict__ bias, const float* __restrict__ bias2,
    int splice, int V, float* __restrict__ part, int nchunk,
    bf16* __restrict__ Out, int strideOut, int dX) {
  constexpr int BK = 64;
  constexpr int KG = 8;                         // granules per row
  constexpr int NIT = KDIM / BK;
  __shared__ bf16 Alds[2][128 * BK];
  __shared__ bf16 Blds[2][128 * BK];
  __shared__ float wpart[2][128];

  const int tid = threadIdx.x;
  const int w = tid >> 6, lane = tid & 63;
  const int q = lane >> 4, c = lane & 15;
  const int wr = w >> 1, wc = w & 1;

  int f = blockIdx.x;
  int xr = f & 7, rb = (f >> 3) & 7, cq = f >> 6;
  int chunk = cq * 8 + xr;
  if (chunk >= nchunk) return;
  const int row0 = rb * 128, col0 = chunk * 128;
  if (cntp && row0 >= *cntp) return;

  int arow[4];
#pragma unroll
  for (int i = 0; i < 4; ++i) {
    int g = i * 256 + tid;
    int r = row0 + (g >> 3);
    arow[i] = rmap ? rmap[r] : r;
  }

  // stage K-tile kt into LDS buffer pb (8 async16 per thread)
  auto stage = [&](int kt, int pb) {
    const int k0 = kt * BK;
#pragma unroll
    for (int i = 0; i < 4; ++i) {
      int g = i * 256 + tid;
      int col = g >> 3, j = g & 7;
      int kg = j ^ (col & 7);
      async16(A + (size_t)arow[i] * strideA + k0 + kg * 8,
              &Alds[pb][(size_t)(g & ~63) * 8]);
      async16(B + (size_t)(col0 + col) * KDIM + k0 + kg * 8,
              &Blds[pb][(size_t)(g & ~63) * 8]);
    }
  };

  f32x4 acc[4][4] = {};

  stage(0, 0);
  for (int kt = 0; kt < NIT; ++kt) {
    const int cb = kt & 1;
    if (kt + 1 < NIT) {
      stage(kt + 1, cb ^ 1);
      // tile kt's 8 loads (issued last iter) retire; kt+1's 8 stay in flight
      asm volatile("s_waitcnt vmcnt(8)" ::: "memory");
    } else {
      asm volatile("s_waitcnt vmcnt(0)" ::: "memory");
    }
    __builtin_amdgcn_sched_barrier(0);
    __builtin_amdgcn_s_barrier();
    asm volatile("" ::: "memory");
    __builtin_amdgcn_s_setprio(1);
#pragma unroll
    for (int ks = 0; ks < BK / 32; ++ks) {
      bf16x8 af[4], bfr[4];
#pragma unroll
      for (int rt = 0; rt < 4; ++rt) {
        int rl = wr * 64 + rt * 16 + c;
        int kq = ks * 4 + q;
        int kg = kq ^ (rl & 7);
        af[rt] = *(const bf16x8*)&Alds[cb][((size_t)rl * KG + kg) * 8];
      }
#pragma unroll
      for (int ct = 0; ct < 4; ++ct) {
        int cl = wc * 64 + ct * 16 + c;
        int kq = ks * 4 + q;
        int kg = kq ^ (cl & 7);
        bfr[ct] = *(const bf16x8*)&Blds[cb][((size_t)cl * KG + kg) * 8];
      }
#pragma unroll
      for (int rt = 0; rt < 4; ++rt)
#pragma unroll
        for (int ct = 0; ct < 4; ++ct)
          acc[rt][ct] = mfma16x16x32(af[rt], bfr[ct], acc[rt][ct]);
    }
    __builtin_amdgcn_s_setprio(0);
    // fence dbuf reuse: all waves' MFMA operand reads retired (register-use
    // forces lgkmcnt drain) before next iteration's stage overwrites cb^1... cb.
    asm volatile("" ::: "memory");
    __builtin_amdgcn_s_barrier();
  }

  if (!LSE) {
#pragma unroll
    for (int rt = 0; rt < 4; ++rt)
#pragma unroll
      for (int ct = 0; ct < 4; ++ct)
#pragma unroll
        for (int r = 0; r < 4; ++r) {
          int col = col0 + wc * 64 + ct * 16 + c;
          if (col < dX) {
            int row = row0 + wr * 64 + rt * 16 + q * 4 + r;
            Out[(size_t)row * strideOut + col] = (bf16)acc[rt][ct][r];
          }
        }
    return;
  }

  // ---- LSE epilogue, M=0 (logit spread << 87: exp cannot overflow) ----
  float bv[4];
#pragma unroll
  for (int ct = 0; ct < 4; ++ct) {
    int colg = col0 + wc * 64 + ct * 16 + c;
    bv[ct] = (colg < V) ? ((colg < splice) ? bias[colg] : bias2[colg - splice]) : -INFINITY;
  }
#pragma unroll
  for (int rt = 0; rt < 4; ++rt) {
#pragma unroll
    for (int r = 0; r < 4; ++r) {
      float s = 0.f;
#pragma unroll
      for (int ct = 0; ct < 4; ++ct) s += __expf(acc[rt][ct][r] + bv[ct]);
#pragma unroll
      for (int off = 1; off <= 8; off <<= 1) s += __shfl_xor(s, off);
      if (c == 0) wpart[wc][wr * 64 + rt * 16 + q * 4 + r] = s;
    }
  }
  __syncthreads();
  if (tid < 128)
    part[(size_t)chunk * 1024 + row0 + tid] = __logf(wpart[0][tid] + wpart[1][tid]);
}

// ---------------- wide tail GEMM+LSE: K fully resident, G chunks/block ----------------
// cluster 2: K=64, cluster 3: K=32. A-tile staged ONCE, A-fragments hoisted to
// registers. B 3-buffered with DEPTH-2 prefetch and counted vmcnt (never 0 in
// the loop). Bias pre-staged to LDS; running exp-sums in registers across all
// G chunks; one shuffle-reduce + one partial write per block.
template <int KDIM, int G>
__global__ void __launch_bounds__(256) gemm_lse_wide_kernel(
    const bf16* __restrict__ A, int strideA,
    const int* __restrict__ rmap, const int* __restrict__ cntp,
    const bf16* __restrict__ B, const float* __restrict__ bias,
    int V, float* __restrict__ part, int nchunk) {
  constexpr int BK = KDIM;          // 32 or 64
  constexpr int KG = BK / 8;        // granules per row
  constexpr int NL = KG / 2;        // async16 issued per thread per B-chunk
  __shared__ bf16 Alds[128 * BK];
  __shared__ bf16 Blds[3][128 * BK];
  __shared__ float biasl[G * 128];
  __shared__ float spart[2][128];

  const int tid = threadIdx.x;
  const int w = tid >> 6, lane = tid & 63;
  const int q = lane >> 4, c = lane & 15;
  const int wr = w >> 1, wc = w & 1;

  const int row0 = blockIdx.y * 128;
  if (row0 >= *cntp) return;
  const int chunk0 = blockIdx.x * G;
  const int nc = (nchunk - chunk0 < G) ? (nchunk - chunk0) : G;

  // ---- prologue: bias slab -> LDS, A once, B chunks 0 and 1 ----
  for (int i = tid; i < G * 128; i += 256) {
    int colg = chunk0 * 128 + i;
    biasl[i] = (colg < V) ? bias[colg] : -INFINITY;
  }
#pragma unroll
  for (int i = 0; i < NL; ++i) {
    int g = i * 256 + tid;
    int row = g / KG, j = g % KG;
    int kg = (KG == 8) ? (j ^ (row & 7)) : (j ^ ((row >> 1) & 3));
    int ar = rmap[row0 + row];
    async16(A + (size_t)ar * strideA + kg * 8, &Alds[(size_t)(g & ~63) * 8]);
  }
#pragma unroll
  for (int b = 0; b < 2; ++b) {
    int ck = (b < nc) ? b : nc - 1;
#pragma unroll
    for (int i = 0; i < NL; ++i) {
      int g = i * 256 + tid;
      int col = g / KG, j = g % KG;
      int kg = (KG == 8) ? (j ^ (col & 7)) : (j ^ ((col >> 1) & 3));
      async16(B + (size_t)((chunk0 + ck) * 128 + col) * KDIM + kg * 8,
              &Blds[b][(size_t)(g & ~63) * 8]);
    }
  }
  __syncthreads();  // one-time full drain

  // A fragments live in registers for the whole block
  bf16x8 af[BK / 32][4];
#pragma unroll
  for (int ks = 0; ks < BK / 32; ++ks)
#pragma unroll
    for (int rt = 0; rt < 4; ++rt) {
      int rl = wr * 64 + rt * 16 + c;
      int kq = ks * 4 + q;
      int kg = (KG == 8) ? (kq ^ (rl & 7)) : (kq ^ ((rl >> 1) & 3));
      af[ks][rt] = *(const bf16x8*)&Alds[((size_t)rl * KG + kg) * 8];
    }

  float sums[4][4] = {};  // [rt][r] running exp-sums across chunks
  int ib = 0;             // buffer holding chunk ci

  for (int ci = 0; ci < nc; ++ci) {
    // depth-2 prefetch: chunk ci+2 (clamped so NL stays constant) into (ib+2)%3
    {
      int pre = (ci + 2 < nc) ? ci + 2 : nc - 1;
      bf16* bw = Blds[(ib == 0) ? 2 : ib - 1];
#pragma unroll
      for (int i = 0; i < NL; ++i) {
        int g = i * 256 + tid;
        int col = g / KG, j = g % KG;
        int kg = (KG == 8) ? (j ^ (col & 7)) : (j ^ ((col >> 1) & 3));
        async16(B + (size_t)((chunk0 + pre) * 128 + col) * KDIM + kg * 8,
                &bw[(size_t)(g & ~63) * 8]);
      }
    }

    const bf16* Bl = Blds[ib];
    f32x4 acc[4][4] = {};
#pragma unroll
    for (int ks = 0; ks < BK / 32; ++ks) {
      bf16x8 bfr[4];
#pragma unroll
      for (int ct = 0; ct < 4; ++ct) {
        int cl = wc * 64 + ct * 16 + c;
        int kq = ks * 4 + q;
        int kg = (KG == 8) ? (kq ^ (cl & 7)) : (kq ^ ((cl >> 1) & 3));
        bfr[ct] = *(const bf16x8*)&Bl[((size_t)cl * KG + kg) * 8];
      }
#pragma unroll
      for (int rt = 0; rt < 4; ++rt)
#pragma unroll
        for (int ct = 0; ct < 4; ++ct)
          acc[rt][ct] = mfma16x16x32(af[ks][rt], bfr[ct], acc[rt][ct]);
    }

    // running exp-sum epilogue (bias from LDS: no vmem in loop)
    float bv[4];
#pragma unroll
    for (int ct = 0; ct < 4; ++ct) bv[ct] = biasl[ci * 128 + wc * 64 + ct * 16 + c];
#pragma unroll
    for (int rt = 0; rt < 4; ++rt)
#pragma unroll
      for (int r = 0; r < 4; ++r) {
#pragma unroll
        for (int ct = 0; ct < 4; ++ct)
          sums[rt][r] += __expf(acc[rt][ct][r] + bv[ct]);
      }

    // counted wait: the just-issued batch (NL) stays in flight; the batch for
    // chunk ci+1 (issued last iteration) is guaranteed landed.
    if constexpr (NL == 4) asm volatile("s_waitcnt vmcnt(4)" ::: "memory");
    else                   asm volatile("s_waitcnt vmcnt(2)" ::: "memory");
    __builtin_amdgcn_sched_barrier(0);
    __builtin_amdgcn_s_barrier();
    ib = (ib == 2) ? 0 : ib + 1;
  }

  // ---- once per block: reduce over the 16 c-lanes, combine wc halves, write ----
#pragma unroll
  for (int rt = 0; rt < 4; ++rt)
#pragma unroll
    for (int r = 0; r < 4; ++r) {
      float s = sums[rt][r];
#pragma unroll
      for (int off = 1; off <= 8; off <<= 1) s += __shfl_xor(s, off);
      if (c == 0) spart[wc][wr * 64 + rt * 16 + q * 4 + r] = s;
    }
  __syncthreads();  // full drain: also retires the clamped tail prefetches
  if (tid < 128)
    part[(size_t)blockIdx.x * 1024 + row0 + tid] = __logf(spart[0][tid] + spart[1][tid]);
}

// ---------------- final combine ----------------
__device__ __forceinline__ float wave_sum64(float v) {
#pragma unroll
  for (int off = 1; off < 64; off <<= 1) v += __shfl_xor(v, off);
  return v;
}
// chunk-major partials p[i*1024 + idx] hold log(sum exp) per chunk-group; values
// are small, so a single direct exp-sum pass is exact and safe.
__device__ float lse_cm(const float* __restrict__ p, int n, int idx) {
  int lane = threadIdx.x & 63;
  float s = 0.f;
  for (int i = lane; i < n; i += 64) s += __expf(p[(size_t)i * 1024 + idx]);
  s = wave_sum64(s);
  return __logf(s);
}
__device__ float dot_bw(const bf16* __restrict__ h, const float* __restrict__ wv, int K) {
  int lane = threadIdx.x & 63;
  float s = 0.f;
  for (int i = lane; i < K; i += 64) s += (float)h[i] * wv[i];
  return wave_sum64(s);
}

__global__ void __launch_bounds__(256) final_kernel(
    const int* __restrict__ target, const int* __restrict__ slotmap,
    const float* __restrict__ pH, const float* __restrict__ p1,
    const float* __restrict__ p2, const float* __restrict__ p3,
    const bf16* __restrict__ Hcat,
    const float* __restrict__ head_w, const float* __restrict__ head_b,
    const float* __restrict__ cluster_w, const float* __restrict__ cluster_b,
    const float* __restrict__ w1, const float* __restrict__ b1,
    const float* __restrict__ w2, const float* __restrict__ b2,
    const float* __restrict__ w3, const float* __restrict__ b3,
    float* __restrict__ out) {
  int wv = threadIdx.x >> 6, lane = threadIdx.x & 63;
  int row = blockIdx.x * 4 + wv;
  int t = target[row];
  const bf16* h0 = Hcat + (size_t)row * 1408;

  float lseH = lse_cm(pH, 157, row);
  float lp;
  if (t < 20000) {
    float sel = dot_bw(h0, head_w + (size_t)t * 1024, 1024) + head_b[t];
    lp = sel - lseH;
  } else {
    int i, L, KW, nch, hoff;
    const float* pp; const float* W; const float* Bb;
    if (t < 40000)        { i = 1; L = 20000;  KW = 256; nch = 157; hoff = 1024; pp = p1; W = w1; Bb = b1; }
    else if (t < 200000)  { i = 2; L = 40000;  KW = 64;  nch = 157; hoff = 1280; pp = p2; W = w2; Bb = b2; }
    else                  { i = 3; L = 200000; KW = 16;  nch = 67;  hoff = 1344; pp = p3; W = w3; Bb = b3; }
    int slot = slotmap[row];
    float lseT = lse_cm(pp, nch, slot);
    int ti = t - L;
    float tsel = dot_bw(h0 + hoff, W + (size_t)ti * KW, KW) + Bb[ti];
    int j = 3 - i;  // head_lp[:, -i] == cluster row (3-i)
    float csel = dot_bw(h0, cluster_w + (size_t)j * 1024, 1024) + cluster_b[j];
    lp = (csel - lseH) + (tsel - lseT);
  }
  if (lane == 0) out[row] = -lp;
}

extern "C" void kernel_launch(void* const* d_in, const int* in_sizes, int n_in,
                              void* d_out, int out_size, void* d_ws, size_t ws_size,
                              hipStream_t stream) {
  (void)in_sizes; (void)n_in; (void)out_size; (void)ws_size;
  const float* hidden    = (const float*)d_in[0];
  const int*   target    = (const int*)d_in[1];
  const float* head_w    = (const float*)d_in[2];
  const float* head_b    = (const float*)d_in[3];
  const float* cluster_w = (const float*)d_in[4];
  const float* cluster_b = (const float*)d_in[5];
  const float* proj0     = (const float*)d_in[6];
  const float* proj1     = (const float*)d_in[7];
  const float* proj2     = (const float*)d_in[8];
  const float* proj3     = (const float*)d_in[9];
  const float* w1 = (const float*)d_in[10];
  const float* b1 = (const float*)d_in[11];
  const float* w2 = (const float*)d_in[12];
  const float* b2 = (const float*)d_in[13];
  const float* w3 = (const float*)d_in[14];
  const float* b3 = (const float*)d_in[15];
  float* out = (float*)d_out;

  char* p = (char*)d_ws;
  bf16* hid_b = (bf16*)p; p += (size_t)1024 * 1024 * 2;
  bf16* Hcat  = (bf16*)p; p += (size_t)1024 * 1408 * 2;  // h0|h1|h2|h3 stride 1408
  bf16* Pcat  = (bf16*)p; p += (size_t)1408 * 1024 * 2;  // P0t|P1t|P2t|P3t stacked
  bf16* Wh    = (bf16*)p; p += (size_t)20096 * 1024 * 2; // head_w ++ cluster_w (++ zero pad)
  bf16* W1b   = (bf16*)p; p += (size_t)20096 * 256 * 2;
  bf16* W2b   = (bf16*)p; p += (size_t)160000 * 64 * 2;
  bf16* W3b   = (bf16*)p; p += (size_t)67840 * 32 * 2;
  float* pH   = (float*)p; p += (size_t)157 * 1024 * 4;
  float* p1   = (float*)p; p += (size_t)157 * 1024 * 4;
  float* p2   = (float*)p; p += (size_t)1250 * 1024 * 4;
  float* p3   = (float*)p; p += (size_t)530 * 1024 * 4;
  int* rowmap = (int*)p;  p += 3 * 1152 * 4;
  int* slotmap= (int*)p;  p += 1024 * 4;
  int* counts = (int*)p;  p += 3 * 4;

  compact_kernel<<<1, 1024, 0, stream>>>(target, rowmap, slotmap, counts);

  // ---- all weight/input conversions: 2 launches total ----
  megaconvert_kernel<<<37204, 256, 0, stream>>>(hidden, head_w, cluster_w, w1, w2, w3,
                                                hid_b, Wh, W1b, W2b, W3b);
  transpose_all_kernel<<<dim3(32, 43), 256, 0, stream>>>(proj0, proj1, proj2, proj3, Pcat);

  // ---- all projections in one GEMM: Hcat[1024][1376] = hid_b @ Pcat^T ----
  gemm_kernel<1024, false><<<128, 256, 0, stream>>>(hid_b, 1024, nullptr, nullptr, Pcat,
                                                    nullptr, nullptr, 0, 0, nullptr, 11,
                                                    Hcat, 1408, 1376);

  // ---- head + cluster-1: counted-vmcnt pipelined GEMM with fused chunk LSE ----
  gemm_kernel<1024, true><<<64 * 20, 256, 0, stream>>>(Hcat, 1408, nullptr, nullptr, Wh,
                                                       head_b, cluster_b, 20000, 20003,
                                                       pH, 157, nullptr, 0, 0);
  gemm_kernel<256, true><<<64 * 20, 256, 0, stream>>>(Hcat + 1024, 1408, rowmap, counts, W1b,
                                                      b1, b1, 0x40000000, 20000,
                                                      p1, 157, nullptr, 0, 0);

  // ---- cluster 2/3: K-resident wide kernel, depth-2 counted-vmcnt pipeline ----
  gemm_lse_wide_kernel<64, 8><<<dim3(157, 8), 256, 0, stream>>>(
      Hcat + 1280, 1408, rowmap + 1152, counts + 1, W2b, b2, 160000, p2, 1250);
  gemm_lse_wide_kernel<32, 8><<<dim3(67, 8), 256, 0, stream>>>(
      Hcat + 1344, 1408, rowmap + 2304, counts + 2, W3b, b3, 67735, p3, 530);

  final_kernel<<<256, 256, 0, stream>>>(target, slotmap, pH, p1, p2, p3, Hcat,
                                        head_w, head_b, cluster_w, cluster_b,
                                        w1, b1, w2, b2, w3, b3, out);
}

// Round 6
// 372.273 us; speedup vs baseline: 1.0932x; 1.0282x over previous
//
#include <hip/hip_runtime.h>
#include <math.h>

typedef __bf16 bf16;
typedef __bf16 bf16x4 __attribute__((ext_vector_type(4)));
typedef __bf16 bf16x8 __attribute__((ext_vector_type(8)));
typedef float  f32x4  __attribute__((ext_vector_type(4)));

__device__ __forceinline__ f32x4 mfma16x16x32(bf16x8 a, bf16x8 b, f32x4 c) {
  return __builtin_amdgcn_mfma_f32_16x16x32_bf16(a, b, c, 0, 0, 0);
}

// async 16B global -> LDS (lane data lands at ldsbase + lane*16)
__device__ __forceinline__ void async16(const bf16* gp, bf16* lp) {
  __builtin_amdgcn_global_load_lds(
      (const __attribute__((address_space(1))) void*)gp,
      (__attribute__((address_space(3))) void*)lp, 16, 0, 0);
}

// ---------------- fused fp32 -> bf16 conversion (single launch) ----------------
__global__ void __launch_bounds__(256) megaconvert_kernel(
    const float* __restrict__ hidden, const float* __restrict__ head_w,
    const float* __restrict__ cluster_w, const float* __restrict__ w1,
    const float* __restrict__ w2, const float* __restrict__ w3,
    bf16* __restrict__ hid_b, bf16* __restrict__ Wh, bf16* __restrict__ W1b,
    bf16* __restrict__ W2b, bf16* __restrict__ W3b) {
  int b = blockIdx.x;
  const float* in; bf16* out; int n4, tot; int w3mode = 0;
  if (b < 1024)       { in = hidden;    out = hid_b; n4 = 262144;  tot = 262144;  }
  else if (b < 21024) { in = head_w;    out = Wh;    n4 = 5120000; tot = 5120000; b -= 1024; }
  else if (b < 21120) { in = cluster_w; out = Wh + (size_t)20000 * 1024; n4 = 768; tot = 24576; b -= 21024; }
  else if (b < 26144) { in = w1;        out = W1b;   n4 = 1280000; tot = 1286144; b -= 21120; }
  else if (b < 36144) { in = w2;        out = W2b;   n4 = 2560000; tot = 2560000; b -= 26144; }
  else                { in = w3;        out = W3b;   n4 = 270940;  tot = 271360;  b -= 36144; w3mode = 1; }
  int i = b * 256 + threadIdx.x;
  if (i >= tot) return;
  bf16x4 z = {(bf16)0.f, (bf16)0.f, (bf16)0.f, (bf16)0.f};
  bf16x4 v = z;
  if (i < n4) {
    float4 f = ((const float4*)in)[i];
    v = (bf16x4){(bf16)f.x, (bf16)f.y, (bf16)f.z, (bf16)f.w};
  }
  if (!w3mode) {
    ((bf16x4*)out)[i] = v;
  } else {
    int row = i >> 2, kq = i & 3;
    *(bf16x4*)&out[(size_t)row * 32 + kq * 4] = v;
    *(bf16x4*)&out[(size_t)row * 32 + 16 + kq * 4] = z;
  }
}

// ---------------- all 4 projections: transpose+convert in one launch ----------------
__global__ void __launch_bounds__(256) transpose_all_kernel(
    const float* __restrict__ proj0, const float* __restrict__ proj1,
    const float* __restrict__ proj2, const float* __restrict__ proj3,
    bf16* __restrict__ Pcat) {
  __shared__ float t[32][33];
  int y = blockIdx.y;
  const float* P; bf16* Pt; int dX, cy;
  if (y < 32)      { P = proj0; Pt = Pcat;                        dX = 1024; cy = y; }
  else if (y < 40) { P = proj1; Pt = Pcat + (size_t)1024 * 1024;  dX = 256;  cy = y - 32; }
  else if (y < 42) { P = proj2; Pt = Pcat + (size_t)1280 * 1024;  dX = 64;   cy = y - 40; }
  else             { P = proj3; Pt = Pcat + (size_t)1344 * 1024;  dX = 16;   cy = y - 42; }
  int tx = threadIdx.x & 31, ty = threadIdx.x >> 5;
  int k0 = blockIdx.x * 32, c0 = cy * 32;
#pragma unroll
  for (int s = 0; s < 4; ++s) {
    int k = k0 + ty + s * 8, col = c0 + tx;
    t[ty + s * 8][tx] = (col < dX) ? P[(size_t)k * dX + col] : 0.f;
  }
  __syncthreads();
#pragma unroll
  for (int s = 0; s < 4; ++s) {
    int colo = c0 + ty + s * 8;
    Pt[(size_t)colo * 1024 + k0 + tx] = (bf16)t[tx][ty + s * 8];
  }
}

// ---------------- row compaction by target cluster ----------------
__global__ void __launch_bounds__(1024) compact_kernel(const int* __restrict__ target,
                                                       int* __restrict__ rowmap,
                                                       int* __restrict__ slotmap,
                                                       int* __restrict__ counts) {
  __shared__ int cnt[3];
  int tid = threadIdx.x;
  if (tid < 3) cnt[tid] = 0;
  for (int i = tid; i < 3 * 1152; i += 1024) rowmap[i] = 0;
  __syncthreads();
  int t = target[tid];
  int c = (t >= 200000) ? 2 : (t >= 40000) ? 1 : (t >= 20000) ? 0 : -1;
  int slot = -1;
  if (c >= 0) {
    slot = atomicAdd(&cnt[c], 1);
    rowmap[c * 1152 + slot] = tid;
  }
  slotmap[tid] = slot;
  __syncthreads();
  if (tid < 3) counts[tid] = cnt[tid];
}

// ---------- unified MFMA GEMM: BK=128 serial 2-barrier, split-half LDS ----------
// Each 128-wide K-tile is stored as TWO [128][64] subtiles, each with the KG=8
// XOR layout measured at 0 bank conflicts (R1/R5). This keeps R4's amortization
// (64 MFMA per staging drain, 2 barriers per 128 K) while eliminating R4's 5.1M
// conflict cycles (256B-row-stride pathology). Occupancy is VGPR-capped at
// 2 blocks/CU, so the 64KB LDS footprint is free.
template <int KDIM, bool LSE>
__global__ void __launch_bounds__(256) gemm_kernel(
    const bf16* __restrict__ A, int strideA,
    const int* __restrict__ rmap, const int* __restrict__ cntp,
    const bf16* __restrict__ B,
    const float* __restrict__ bias, const float* __restrict__ bias2,
    int splice, int V, float* __restrict__ part, int nchunk,
    bf16* __restrict__ Out, int strideOut, int dX) {
  constexpr int BK = 128;
  constexpr int NIT = KDIM / BK;
  __shared__ bf16 Alds[2][128 * 64];
  __shared__ bf16 Blds[2][128 * 64];
  __shared__ float wpart[2][128];

  const int tid = threadIdx.x;
  const int w = tid >> 6, lane = tid & 63;
  const int q = lane >> 4, c = lane & 15;
  const int wr = w >> 1, wc = w & 1;

  int f = blockIdx.x;
  int xr = f & 7, rb = (f >> 3) & 7, cq = f >> 6;
  int chunk = cq * 8 + xr;
  if (chunk >= nchunk) return;
  const int row0 = rb * 128, col0 = chunk * 128;
  if (cntp && row0 >= *cntp) return;

  int arow[4];
#pragma unroll
  for (int i = 0; i < 4; ++i) {
    int g = i * 256 + tid;
    int r = row0 + (g >> 3);
    arow[i] = rmap ? rmap[r] : r;
  }

  f32x4 acc[4][4] = {};

  for (int kt = 0; kt < NIT; ++kt) {
    const int k0 = kt * BK;
    // stage both halves: per half, the proven KG=8 wave-uniform-dest pattern
#pragma unroll
    for (int h = 0; h < 2; ++h)
#pragma unroll
      for (int i = 0; i < 4; ++i) {
        int g = i * 256 + tid;
        int row = g >> 3, jj = g & 7;
        int kg = jj ^ (row & 7);
        async16(A + (size_t)arow[i] * strideA + k0 + h * 64 + kg * 8,
                &Alds[h][(size_t)(g & ~63) * 8]);
        async16(B + (size_t)(col0 + row) * KDIM + k0 + h * 64 + kg * 8,
                &Blds[h][(size_t)(g & ~63) * 8]);
      }
    __syncthreads();  // drain: amortized over 64 MFMA below
#pragma unroll
    for (int ks = 0; ks < 4; ++ks) {
      const bf16* Ah = Alds[ks >> 1];
      const bf16* Bh = Blds[ks >> 1];
      const int kqb = (ks & 1) * 4 + q;
      bf16x8 af[4], bfr[4];
#pragma unroll
      for (int rt = 0; rt < 4; ++rt) {
        int rl = wr * 64 + rt * 16 + c;
        int kg = kqb ^ (rl & 7);
        af[rt] = *(const bf16x8*)&Ah[((size_t)rl * 8 + kg) * 8];
      }
#pragma unroll
      for (int ct = 0; ct < 4; ++ct) {
        int cl = wc * 64 + ct * 16 + c;
        int kg = kqb ^ (cl & 7);
        bfr[ct] = *(const bf16x8*)&Bh[((size_t)cl * 8 + kg) * 8];
      }
#pragma unroll
      for (int rt = 0; rt < 4; ++rt)
#pragma unroll
        for (int ct = 0; ct < 4; ++ct)
          acc[rt][ct] = mfma16x16x32(af[rt], bfr[ct], acc[rt][ct]);
    }
    __syncthreads();  // fence buffer reuse before next stage
  }

  if (!LSE) {
#pragma unroll
    for (int rt = 0; rt < 4; ++rt)
#pragma unroll
      for (int ct = 0; ct < 4; ++ct)
#pragma unroll
        for (int r = 0; r < 4; ++r) {
          int col = col0 + wc * 64 + ct * 16 + c;
          if (col < dX) {
            int row = row0 + wr * 64 + rt * 16 + q * 4 + r;
            Out[(size_t)row * strideOut + col] = (bf16)acc[rt][ct][r];
          }
        }
    return;
  }

  // ---- LSE epilogue, M=0 (logit spread << 87: exp cannot overflow) ----
  float bv[4];
#pragma unroll
  for (int ct = 0; ct < 4; ++ct) {
    int colg = col0 + wc * 64 + ct * 16 + c;
    bv[ct] = (colg < V) ? ((colg < splice) ? bias[colg] : bias2[colg - splice]) : -INFINITY;
  }
#pragma unroll
  for (int rt = 0; rt < 4; ++rt) {
#pragma unroll
    for (int r = 0; r < 4; ++r) {
      float s = 0.f;
#pragma unroll
      for (int ct = 0; ct < 4; ++ct) s += __expf(acc[rt][ct][r] + bv[ct]);
#pragma unroll
      for (int off = 1; off <= 8; off <<= 1) s += __shfl_xor(s, off);
      if (c == 0) wpart[wc][wr * 64 + rt * 16 + q * 4 + r] = s;
    }
  }
  __syncthreads();
  if (tid < 128)
    part[(size_t)chunk * 1024 + row0 + tid] = __logf(wpart[0][tid] + wpart[1][tid]);
}

// ---------------- wide tail GEMM+LSE: K fully resident, G chunks/block ----------------
// cluster 2: K=64, cluster 3: K=32. A-tile staged ONCE, A-fragments hoisted to
// registers. B 3-buffered with DEPTH-2 prefetch and counted vmcnt (never 0 in
// the loop). Bias pre-staged to LDS; running exp-sums in registers across all
// G chunks; one shuffle-reduce + one partial write per block.
template <int KDIM, int G>
__global__ void __launch_bounds__(256) gemm_lse_wide_kernel(
    const bf16* __restrict__ A, int strideA,
    const int* __restrict__ rmap, const int* __restrict__ cntp,
    const bf16* __restrict__ B, const float* __restrict__ bias,
    int V, float* __restrict__ part, int nchunk) {
  constexpr int BK = KDIM;          // 32 or 64
  constexpr int KG = BK / 8;        // granules per row
  constexpr int NL = KG / 2;        // async16 issued per thread per B-chunk
  __shared__ bf16 Alds[128 * BK];
  __shared__ bf16 Blds[3][128 * BK];
  __shared__ float biasl[G * 128];
  __shared__ float spart[2][128];

  const int tid = threadIdx.x;
  const int w = tid >> 6, lane = tid & 63;
  const int q = lane >> 4, c = lane & 15;
  const int wr = w >> 1, wc = w & 1;

  const int row0 = blockIdx.y * 128;
  if (row0 >= *cntp) return;
  const int chunk0 = blockIdx.x * G;
  const int nc = (nchunk - chunk0 < G) ? (nchunk - chunk0) : G;

  // ---- prologue: bias slab -> LDS, A once, B chunks 0 and 1 ----
  for (int i = tid; i < G * 128; i += 256) {
    int colg = chunk0 * 128 + i;
    biasl[i] = (colg < V) ? bias[colg] : -INFINITY;
  }
#pragma unroll
  for (int i = 0; i < NL; ++i) {
    int g = i * 256 + tid;
    int row = g / KG, j = g % KG;
    int kg = (KG == 8) ? (j ^ (row & 7)) : (j ^ ((row >> 1) & 3));
    int ar = rmap[row0 + row];
    async16(A + (size_t)ar * strideA + kg * 8, &Alds[(size_t)(g & ~63) * 8]);
  }
#pragma unroll
  for (int b = 0; b < 2; ++b) {
    int ck = (b < nc) ? b : nc - 1;
#pragma unroll
    for (int i = 0; i < NL; ++i) {
      int g = i * 256 + tid;
      int col = g / KG, j = g % KG;
      int kg = (KG == 8) ? (j ^ (col & 7)) : (j ^ ((col >> 1) & 3));
      async16(B + (size_t)((chunk0 + ck) * 128 + col) * KDIM + kg * 8,
              &Blds[b][(size_t)(g & ~63) * 8]);
    }
  }
  __syncthreads();  // one-time full drain

  // A fragments live in registers for the whole block
  bf16x8 af[BK / 32][4];
#pragma unroll
  for (int ks = 0; ks < BK / 32; ++ks)
#pragma unroll
    for (int rt = 0; rt < 4; ++rt) {
      int rl = wr * 64 + rt * 16 + c;
      int kq = ks * 4 + q;
      int kg = (KG == 8) ? (kq ^ (rl & 7)) : (kq ^ ((rl >> 1) & 3));
      af[ks][rt] = *(const bf16x8*)&Alds[((size_t)rl * KG + kg) * 8];
    }

  float sums[4][4] = {};  // [rt][r] running exp-sums across chunks
  int ib = 0;             // buffer holding chunk ci

  for (int ci = 0; ci < nc; ++ci) {
    // depth-2 prefetch: chunk ci+2 (clamped so NL stays constant) into (ib+2)%3
    {
      int pre = (ci + 2 < nc) ? ci + 2 : nc - 1;
      bf16* bw = Blds[(ib == 0) ? 2 : ib - 1];
#pragma unroll
      for (int i = 0; i < NL; ++i) {
        int g = i * 256 + tid;
        int col = g / KG, j = g % KG;
        int kg = (KG == 8) ? (j ^ (col & 7)) : (j ^ ((col >> 1) & 3));
        async16(B + (size_t)((chunk0 + pre) * 128 + col) * KDIM + kg * 8,
                &bw[(size_t)(g & ~63) * 8]);
      }
    }

    const bf16* Bl = Blds[ib];
    f32x4 acc[4][4] = {};
#pragma unroll
    for (int ks = 0; ks < BK / 32; ++ks) {
      bf16x8 bfr[4];
#pragma unroll
      for (int ct = 0; ct < 4; ++ct) {
        int cl = wc * 64 + ct * 16 + c;
        int kq = ks * 4 + q;
        int kg = (KG == 8) ? (kq ^ (cl & 7)) : (kq ^ ((cl >> 1) & 3));
        bfr[ct] = *(const bf16x8*)&Bl[((size_t)cl * KG + kg) * 8];
      }
#pragma unroll
      for (int rt = 0; rt < 4; ++rt)
#pragma unroll
        for (int ct = 0; ct < 4; ++ct)
          acc[rt][ct] = mfma16x16x32(af[ks][rt], bfr[ct], acc[rt][ct]);
    }

    // running exp-sum epilogue (bias from LDS: no vmem in loop)
    float bv[4];
#pragma unroll
    for (int ct = 0; ct < 4; ++ct) bv[ct] = biasl[ci * 128 + wc * 64 + ct * 16 + c];
#pragma unroll
    for (int rt = 0; rt < 4; ++rt)
#pragma unroll
      for (int r = 0; r < 4; ++r) {
#pragma unroll
        for (int ct = 0; ct < 4; ++ct)
          sums[rt][r] += __expf(acc[rt][ct][r] + bv[ct]);
      }

    // counted wait: the just-issued batch (NL) stays in flight; the batch for
    // chunk ci+1 (issued last iteration) is guaranteed landed.
    if constexpr (NL == 4) asm volatile("s_waitcnt vmcnt(4)" ::: "memory");
    else                   asm volatile("s_waitcnt vmcnt(2)" ::: "memory");
    __builtin_amdgcn_sched_barrier(0);
    __builtin_amdgcn_s_barrier();
    ib = (ib == 2) ? 0 : ib + 1;
  }

  // ---- once per block: reduce over the 16 c-lanes, combine wc halves, write ----
#pragma unroll
  for (int rt = 0; rt < 4; ++rt)
#pragma unroll
    for (int r = 0; r < 4; ++r) {
      float s = sums[rt][r];
#pragma unroll
      for (int off = 1; off <= 8; off <<= 1) s += __shfl_xor(s, off);
      if (c == 0) spart[wc][wr * 64 + rt * 16 + q * 4 + r] = s;
    }
  __syncthreads();  // full drain: also retires the clamped tail prefetches
  if (tid < 128)
    part[(size_t)blockIdx.x * 1024 + row0 + tid] = __logf(spart[0][tid] + spart[1][tid]);
}

// ---------------- final combine ----------------
__device__ __forceinline__ float wave_sum64(float v) {
#pragma unroll
  for (int off = 1; off < 64; off <<= 1) v += __shfl_xor(v, off);
  return v;
}
// chunk-major partials p[i*1024 + idx] hold log(sum exp) per chunk-group; values
// are small, so a single direct exp-sum pass is exact and safe.
__device__ float lse_cm(const float* __restrict__ p, int n, int idx) {
  int lane = threadIdx.x & 63;
  float s = 0.f;
  for (int i = lane; i < n; i += 64) s += __expf(p[(size_t)i * 1024 + idx]);
  s = wave_sum64(s);
  return __logf(s);
}
__device__ float dot_bw(const bf16* __restrict__ h, const float* __restrict__ wv, int K) {
  int lane = threadIdx.x & 63;
  float s = 0.f;
  for (int i = lane; i < K; i += 64) s += (float)h[i] * wv[i];
  return wave_sum64(s);
}

__global__ void __launch_bounds__(256) final_kernel(
    const int* __restrict__ target, const int* __restrict__ slotmap,
    const float* __restrict__ pH, const float* __restrict__ p1,
    const float* __restrict__ p2, const float* __restrict__ p3,
    const bf16* __restrict__ Hcat,
    const float* __restrict__ head_w, const float* __restrict__ head_b,
    const float* __restrict__ cluster_w, const float* __restrict__ cluster_b,
    const float* __restrict__ w1, const float* __restrict__ b1,
    const float* __restrict__ w2, const float* __restrict__ b2,
    const float* __restrict__ w3, const float* __restrict__ b3,
    float* __restrict__ out) {
  int wv = threadIdx.x >> 6, lane = threadIdx.x & 63;
  int row = blockIdx.x * 4 + wv;
  int t = target[row];
  const bf16* h0 = Hcat + (size_t)row * 1408;

  float lseH = lse_cm(pH, 157, row);
  float lp;
  if (t < 20000) {
    float sel = dot_bw(h0, head_w + (size_t)t * 1024, 1024) + head_b[t];
    lp = sel - lseH;
  } else {
    int i, L, KW, nch, hoff;
    const float* pp; const float* W; const float* Bb;
    if (t < 40000)        { i = 1; L = 20000;  KW = 256; nch = 157; hoff = 1024; pp = p1; W = w1; Bb = b1; }
    else if (t < 200000)  { i = 2; L = 40000;  KW = 64;  nch = 157; hoff = 1280; pp = p2; W = w2; Bb = b2; }
    else                  { i = 3; L = 200000; KW = 16;  nch = 67;  hoff = 1344; pp = p3; W = w3; Bb = b3; }
    int slot = slotmap[row];
    float lseT = lse_cm(pp, nch, slot);
    int ti = t - L;
    float tsel = dot_bw(h0 + hoff, W + (size_t)ti * KW, KW) + Bb[ti];
    int j = 3 - i;  // head_lp[:, -i] == cluster row (3-i)
    float csel = dot_bw(h0, cluster_w + (size_t)j * 1024, 1024) + cluster_b[j];
    lp = (csel - lseH) + (tsel - lseT);
  }
  if (lane == 0) out[row] = -lp;
}

extern "C" void kernel_launch(void* const* d_in, const int* in_sizes, int n_in,
                              void* d_out, int out_size, void* d_ws, size_t ws_size,
                              hipStream_t stream) {
  (void)in_sizes; (void)n_in; (void)out_size; (void)ws_size;
  const float* hidden    = (const float*)d_in[0];
  const int*   target    = (const int*)d_in[1];
  const float* head_w    = (const float*)d_in[2];
  const float* head_b    = (const float*)d_in[3];
  const float* cluster_w = (const float*)d_in[4];
  const float* cluster_b = (const float*)d_in[5];
  const float* proj0     = (const float*)d_in[6];
  const float* proj1     = (const float*)d_in[7];
  const float* proj2     = (const float*)d_in[8];
  const float* proj3     = (const float*)d_in[9];
  const float* w1 = (const float*)d_in[10];
  const float* b1 = (const float*)d_in[11];
  const float* w2 = (const float*)d_in[12];
  const float* b2 = (const float*)d_in[13];
  const float* w3 = (const float*)d_in[14];
  const float* b3 = (const float*)d_in[15];
  float* out = (float*)d_out;

  char* p = (char*)d_ws;
  bf16* hid_b = (bf16*)p; p += (size_t)1024 * 1024 * 2;
  bf16* Hcat  = (bf16*)p; p += (size_t)1024 * 1408 * 2;  // h0|h1|h2|h3 stride 1408
  bf16* Pcat  = (bf16*)p; p += (size_t)1408 * 1024 * 2;  // P0t|P1t|P2t|P3t stacked
  bf16* Wh    = (bf16*)p; p += (size_t)20096 * 1024 * 2; // head_w ++ cluster_w (++ zero pad)
  bf16* W1b   = (bf16*)p; p += (size_t)20096 * 256 * 2;
  bf16* W2b   = (bf16*)p; p += (size_t)160000 * 64 * 2;
  bf16* W3b   = (bf16*)p; p += (size_t)67840 * 32 * 2;
  float* pH   = (float*)p; p += (size_t)157 * 1024 * 4;
  float* p1   = (float*)p; p += (size_t)157 * 1024 * 4;
  float* p2   = (float*)p; p += (size_t)1250 * 1024 * 4;
  float* p3   = (float*)p; p += (size_t)530 * 1024 * 4;
  int* rowmap = (int*)p;  p += 3 * 1152 * 4;
  int* slotmap= (int*)p;  p += 1024 * 4;
  int* counts = (int*)p;  p += 3 * 4;

  compact_kernel<<<1, 1024, 0, stream>>>(target, rowmap, slotmap, counts);

  // ---- all weight/input conversions: 2 launches total ----
  megaconvert_kernel<<<37204, 256, 0, stream>>>(hidden, head_w, cluster_w, w1, w2, w3,
                                                hid_b, Wh, W1b, W2b, W3b);
  transpose_all_kernel<<<dim3(32, 43), 256, 0, stream>>>(proj0, proj1, proj2, proj3, Pcat);

  // ---- all projections in one GEMM: Hcat[1024][1376] = hid_b @ Pcat^T ----
  gemm_kernel<1024, false><<<128, 256, 0, stream>>>(hid_b, 1024, nullptr, nullptr, Pcat,
                                                    nullptr, nullptr, 0, 0, nullptr, 11,
                                                    Hcat, 1408, 1376);

  // ---- head + cluster-1: BK=128 split-half GEMM with fused chunk LSE ----
  gemm_kernel<1024, true><<<64 * 20, 256, 0, stream>>>(Hcat, 1408, nullptr, nullptr, Wh,
                                                       head_b, cluster_b, 20000, 20003,
                                                       pH, 157, nullptr, 0, 0);
  gemm_kernel<256, true><<<64 * 20, 256, 0, stream>>>(Hcat + 1024, 1408, rowmap, counts, W1b,
                                                      b1, b1, 0x40000000, 20000,
                                                      p1, 157, nullptr, 0, 0);

  // ---- cluster 2/3: K-resident wide kernel, depth-2 counted-vmcnt pipeline ----
  gemm_lse_wide_kernel<64, 8><<<dim3(157, 8), 256, 0, stream>>>(
      Hcat + 1280, 1408, rowmap + 1152, counts + 1, W2b, b2, 160000, p2, 1250);
  gemm_lse_wide_kernel<32, 8><<<dim3(67, 8), 256, 0, stream>>>(
      Hcat + 1344, 1408, rowmap + 2304, counts + 2, W3b, b3, 67735, p3, 530);

  final_kernel<<<256, 256, 0, stream>>>(target, slotmap, pH, p1, p2, p3, Hcat,
                                        head_w, head_b, cluster_w, cluster_b,
                                        w1, b1, w2, b2, w3, b3, out);
}